// Round 15
// baseline (368.175 us; speedup 1.0000x reference)
//
#include <hip/hip_runtime.h>
#include <hip/hip_bf16.h>
#include <math.h>

typedef __bf16 bf16x8_t __attribute__((ext_vector_type(8)));
typedef float f32x4 __attribute__((ext_vector_type(4)));
typedef unsigned short ushort8 __attribute__((ext_vector_type(8)));

__device__ inline unsigned short f2bf(float f) {
  unsigned int u = __builtin_bit_cast(unsigned int, f);
  u += 0x7fffu + ((u >> 16) & 1u);
  return (unsigned short)(u >> 16);
}
__device__ inline float b2f(unsigned short s) {
  unsigned int u = ((unsigned int)s) << 16;
  return __builtin_bit_cast(float, u);
}
__device__ inline unsigned int pack2bf(float lo, float hi) {
  return (unsigned int)f2bf(lo) | ((unsigned int)f2bf(hi) << 16);
}

__device__ __forceinline__ void gll16(const void* g, void* l) {
  __builtin_amdgcn_global_load_lds((const __attribute__((address_space(1))) void*)g,
                                   (__attribute__((address_space(3))) void*)l, 16, 0, 0);
}

// ---------- prepass: fp32 -> bf16 convert ----------
__global__ void cvt_k(const float* __restrict__ X, unsigned short* __restrict__ Xb, int total8) {
  int i = blockIdx.x * blockDim.x + threadIdx.x;
  if (i >= total8) return;
  const float4* p = (const float4*)X + 2 * (size_t)i;
  float4 a = p[0], b = p[1];
  ushort8 v;
  v[0] = f2bf(a.x); v[1] = f2bf(a.y); v[2] = f2bf(a.z); v[3] = f2bf(a.w);
  v[4] = f2bf(b.x); v[5] = f2bf(b.y); v[6] = f2bf(b.z); v[7] = f2bf(b.w);
  ((ushort8*)Xb)[i] = v;
}

// ---------- prepass: transpose + convert: Wt[n][k] = bf16(W[k][n]) ----------
__global__ void twc_k(const float* __restrict__ W, unsigned short* __restrict__ Wt, int K, int N) {
  __shared__ float tile[32][33];
  int k0 = blockIdx.x * 32, n0 = blockIdx.y * 32;
  int tx = threadIdx.x, ty = threadIdx.y;  // 32 x 8
#pragma unroll
  for (int i = 0; i < 32; i += 8) tile[ty + i][tx] = W[(size_t)(k0 + ty + i) * N + n0 + tx];
  __syncthreads();
#pragma unroll
  for (int i = 0; i < 32; i += 8)
    Wt[(size_t)(n0 + ty + i) * K + k0 + tx] = f2bf(tile[tx][ty + i]);
}

// ---------- 2-phase pipelined GEMM: C[M][N] = A[M][K] @ Bt[N][K]^T, optional fused RoPE ----------
template <bool OUT_BF16, bool ROPE>
__global__ __launch_bounds__(256) void gemm_tn(const unsigned short* __restrict__ A,
                                               const unsigned short* __restrict__ Bt,
                                               void* __restrict__ Cv, int M, int N, int K,
                                               const float* __restrict__ cs,
                                               const float* __restrict__ sn, int ropeLim) {
  __shared__ __align__(16) unsigned short As[2][128 * 32];
  __shared__ __align__(16) unsigned short Bs[2][128 * 32];
  const int t = threadIdx.x, w = t >> 6, lane = t & 63;
  const int la = lane & 15, lk = lane >> 4;
  const int wr = w >> 1, wc = w & 1;
  const int bm = blockIdx.y * 128, bn = blockIdx.x * 128;
  const int lrow = lane >> 2, lcb = (lane & 3) * 8;

  const unsigned short* Ab = A + (size_t)(bm + (w * 2) * 16 + lrow) * K + lcb;
  const unsigned short* Ab1 = A + (size_t)(bm + (w * 2 + 1) * 16 + lrow) * K + lcb;
  const unsigned short* Bb = Bt + (size_t)(bn + (w * 2) * 16 + lrow) * K + lcb;
  const unsigned short* Bb1 = Bt + (size_t)(bn + (w * 2 + 1) * 16 + lrow) * K + lcb;
  const int c0 = w * 2, c1 = w * 2 + 1;

  f32x4 acc[4][4] = {};

  gll16(Ab, (char*)As[0] + c0 * 1024);
  gll16(Ab1, (char*)As[0] + c1 * 1024);
  gll16(Bb, (char*)Bs[0] + c0 * 1024);
  gll16(Bb1, (char*)Bs[0] + c1 * 1024);

  const int nt = K / 32;
  int cur = 0;
  for (int kt = 0; kt < nt; ++kt) {
    __syncthreads();
    if (kt + 1 < nt) {
      const int kn = (kt + 1) * 32;
      gll16(Ab + kn, (char*)As[cur ^ 1] + c0 * 1024);
      gll16(Ab1 + kn, (char*)As[cur ^ 1] + c1 * 1024);
      gll16(Bb + kn, (char*)Bs[cur ^ 1] + c0 * 1024);
      gll16(Bb1 + kn, (char*)Bs[cur ^ 1] + c1 * 1024);
    }

    bf16x8_t a[4], b[4];
#pragma unroll
    for (int m = 0; m < 4; ++m)
      a[m] = __builtin_bit_cast(
          bf16x8_t, *(const ushort8*)(As[cur] + (wr * 64 + m * 16 + la) * 32 + lk * 8));
#pragma unroll
    for (int n = 0; n < 4; ++n)
      b[n] = __builtin_bit_cast(
          bf16x8_t, *(const ushort8*)(Bs[cur] + (wc * 64 + n * 16 + la) * 32 + lk * 8));
#pragma unroll
    for (int m = 0; m < 4; ++m)
#pragma unroll
      for (int n = 0; n < 4; ++n)
        acc[m][n] = __builtin_amdgcn_mfma_f32_16x16x32_bf16(a[m], b[n], acc[m][n], 0, 0, 0);
    cur ^= 1;
  }

#pragma unroll
  for (int m = 0; m < 4; ++m) {
#pragma unroll
    for (int n = 0; n < 4; ++n) {
      const int col = bn + wc * 64 + n * 16 + la;
      const bool doRope = ROPE && (col < ropeLim);
#pragma unroll
      for (int r = 0; r < 4; ++r) {
        int row = bm + wr * 64 + m * 16 + lk * 4 + r;
        float val = acc[m][n][r];
        if (ROPE) {
          float pval = __shfl_xor(val, 1);
          if (doRope) {
            int srow = row & 2047;
            int i = (col & 127) >> 1;
            float cc = cs[srow * 64 + i], ss = sn[srow * 64 + i];
            val = (la & 1) ? (pval * ss + val * cc) : (val * cc - pval * ss);
          }
        }
        if (OUT_BF16)
          ((unsigned short*)Cv)[(size_t)row * N + col] = f2bf(val);
        else
          ((float*)Cv)[(size_t)row * N + col] = val;
      }
    }
  }
}

// ---------- V transpose: Vt[(b*4+g)*128 + d][s] = QKV[(b*2048+s)*3072 + 2560 + g*128 + d] ----------
__global__ void transpose_v(const unsigned short* __restrict__ QKV, unsigned short* __restrict__ Vt) {
  __shared__ unsigned short tile[32][33];
  int bg = blockIdx.z;
  int b = bg >> 2, g = bg & 3;
  int s0 = blockIdx.x * 32, d0 = blockIdx.y * 32;
  int tx = threadIdx.x, ty = threadIdx.y;  // 32 x 8
#pragma unroll
  for (int i = 0; i < 32; i += 8)
    tile[ty + i][tx] = QKV[((size_t)(b * 2048 + s0 + ty + i)) * 3072 + 2560 + g * 128 + d0 + tx];
  __syncthreads();
#pragma unroll
  for (int i = 0; i < 32; i += 8)
    Vt[((size_t)(bg * 128 + d0 + ty + i)) * 2048 + s0 + tx] = tile[tx][ty + i];
}

// ---------- MFMA flash attention: kv-split + reg-staged single-buffer (48 KB -> 3 blocks/CU) ----------
// 4 waves x 32 q-rows, kv-tile 64, swapped QK^T, packed-P LDS, defer-max.
// grid (24, 16, B): x -> (qt, chunk) heavy-first. Chunks: c0 = kv[0,1024), c1 = kv[1024, qend).
// Partial blocks (qt>=8) emit normalized O (bf16) + (m,l); combine_k merges.
__global__ __launch_bounds__(256, 3) void attn_mfma(const unsigned short* __restrict__ QKV,
                                                    const unsigned short* __restrict__ Vt,
                                                    unsigned short* __restrict__ Ob,
                                                    unsigned short* __restrict__ oP,
                                                    float* __restrict__ mlP) {
  const int S = 2048;
  __shared__ __align__(16) unsigned short Ks[64 * 128];   // 16 KB, swizzled
  __shared__ __align__(16) unsigned short Vs[128 * 64];   // 16 KB, swizzled
  __shared__ __align__(16) unsigned short Ps[4 * 32 * 64]; // 16 KB per-wave P

  const int t = threadIdx.x;
  const int w = t >> 6, lane = t & 63;
  const int la = lane & 15, lk = lane >> 4;
  const int b = blockIdx.z, h = blockIdx.y, g = h >> 2;

  // x -> (qt, c), heavy-first
  int x = blockIdx.x, qt, c;
  if (x < 9) { qt = 7 + x; c = 0; }
  else if (x == 9) { qt = 15; c = 1; }
  else { int k = (x - 10) >> 1; if ((x & 1) == 0) { qt = 6 - k; c = 0; } else { qt = 14 - k; c = 1; } }

  const int qw = qt * 128 + w * 32;
  const int n_full = 2 * qt + 2;
  const int kts = c * 16;
  const int kte = min(n_full, kts + 16);
  const bool full = (kts == 0) && (kte == n_full);
  const float scale = 0.08838834764831845f;  // 1/sqrt(128)

  // staging geometry: K rows 64 x 16 chunks (4 thr/row x 4 chunks), V rows 128 x 8 chunks (2 thr/row x 4)
  const int skr = t >> 2, skc = t & 3;
  const int svr = t >> 1, svc = t & 1;
  const unsigned short* kgp = QKV + (size_t)(b * S + skr) * 3072 + 2048 + g * 128;
  const unsigned short* vgp = Vt + (size_t)((b * 4 + g) * 128 + svr) * 2048;
  char* Ksb = (char*)Ks;
  char* Vsb = (char*)Vs;

  float4 kr0, kr1, kr2, kr3, vr0, vr1, vr2, vr3;
#define LOADR(KT)                                                          \
  do {                                                                     \
    const size_t _ko = (size_t)(KT) * 64;                                  \
    kr0 = *(const float4*)(kgp + _ko * 3072 + (skc + 0) * 8);              \
    kr1 = *(const float4*)(kgp + _ko * 3072 + (skc + 4) * 8);              \
    kr2 = *(const float4*)(kgp + _ko * 3072 + (skc + 8) * 8);              \
    kr3 = *(const float4*)(kgp + _ko * 3072 + (skc + 12) * 8);             \
    vr0 = *(const float4*)(vgp + _ko + (svc + 0) * 8);                     \
    vr1 = *(const float4*)(vgp + _ko + (svc + 2) * 8);                     \
    vr2 = *(const float4*)(vgp + _ko + (svc + 4) * 8);                     \
    vr3 = *(const float4*)(vgp + _ko + (svc + 6) * 8);                     \
  } while (0)
#define WRITEL()                                                             \
  do {                                                                       \
    *(float4*)(Ksb + skr * 256 + (((skc + 0) ^ (skr & 7)) << 4)) = kr0;      \
    *(float4*)(Ksb + skr * 256 + (((skc + 4) ^ (skr & 7)) << 4)) = kr1;      \
    *(float4*)(Ksb + skr * 256 + (((skc + 8) ^ (skr & 7)) << 4)) = kr2;      \
    *(float4*)(Ksb + skr * 256 + (((skc + 12) ^ (skr & 7)) << 4)) = kr3;     \
    *(float4*)(Vsb + svr * 128 + (((svc + 0) ^ (svr & 7)) << 4)) = vr0;      \
    *(float4*)(Vsb + svr * 128 + (((svc + 2) ^ (svr & 7)) << 4)) = vr1;      \
    *(float4*)(Vsb + svr * 128 + (((svc + 4) ^ (svr & 7)) << 4)) = vr2;      \
    *(float4*)(Vsb + svr * 128 + (((svc + 6) ^ (svr & 7)) << 4)) = vr3;      \
  } while (0)

  // Q fragments
  bf16x8_t qf[2][4];
#pragma unroll
  for (int qi = 0; qi < 2; ++qi)
#pragma unroll
    for (int dt = 0; dt < 4; ++dt)
      qf[qi][dt] = __builtin_bit_cast(
          bf16x8_t, *(const ushort8*)(QKV + (size_t)(b * S + qw + qi * 16 + la) * 3072 + h * 128 +
                                      dt * 32 + lk * 8));

  f32x4 oa[2][8];
#pragma unroll
  for (int qi = 0; qi < 2; ++qi)
#pragma unroll
    for (int dt = 0; dt < 8; ++dt) oa[qi][dt] = (f32x4){0.f, 0.f, 0.f, 0.f};
  float mr[2] = {-1e30f, -1e30f}, lr[2] = {0.f, 0.f};

  const int kmask0 = qw & ~63;
  char* pw = (char*)Ps + w * 4096;

  // prologue: stage first tile
  LOADR(kts);
  WRITEL();
  __syncthreads();

  for (int kt = kts; kt < kte; ++kt) {
    const int k0 = kt * 64;
    if (kt + 1 < kte) LOADR(kt + 1);  // HBM/L2 latency hides under compute

    if (k0 <= qw + 31) {  // wave not fully masked
      // swapped QK^T
      f32x4 sacc[2][4];
#pragma unroll
      for (int qi = 0; qi < 2; ++qi)
#pragma unroll
        for (int ktc = 0; ktc < 4; ++ktc) sacc[qi][ktc] = (f32x4){0.f, 0.f, 0.f, 0.f};
      __builtin_amdgcn_s_setprio(1);
#pragma unroll
      for (int ktc = 0; ktc < 4; ++ktc) {
        int row = ktc * 16 + la;
#pragma unroll
        for (int dt = 0; dt < 4; ++dt) {
          bf16x8_t kf = __builtin_bit_cast(
              bf16x8_t, *(const ushort8*)(Ksb + row * 256 + ((((dt << 2) + lk) ^ (row & 7)) << 4)));
          sacc[0][ktc] = __builtin_amdgcn_mfma_f32_16x16x32_bf16(kf, qf[0][dt], sacc[0][ktc], 0, 0, 0);
          sacc[1][ktc] = __builtin_amdgcn_mfma_f32_16x16x32_bf16(kf, qf[1][dt], sacc[1][ktc], 0, 0, 0);
        }
      }
      __builtin_amdgcn_s_setprio(0);

      const bool domask = (k0 == kmask0);
#pragma unroll
      for (int qi = 0; qi < 2; ++qi) {
        const int q = qw + qi * 16 + la;
        float p[4][4];
        float tm = -1e30f;
#pragma unroll
        for (int ktc = 0; ktc < 4; ++ktc)
#pragma unroll
          for (int r = 0; r < 4; ++r) {
            float sv = sacc[qi][ktc][r] * scale;
            if (domask && (k0 + ktc * 16 + lk * 4 + r > q)) sv = -1e30f;
            p[ktc][r] = sv;
            tm = fmaxf(tm, sv);
          }
        tm = fmaxf(tm, __shfl_xor(tm, 16));
        tm = fmaxf(tm, __shfl_xor(tm, 32));
        float mn;
        if (__all(tm - mr[qi] <= 8.f)) {
          mn = mr[qi];
        } else {
          mn = fmaxf(mr[qi], tm);
          float sc = __expf(mr[qi] - mn);
          mr[qi] = mn;
          lr[qi] *= sc;
          float scb[4];
#pragma unroll
          for (int r = 0; r < 4; ++r) scb[r] = __shfl(sc, lk * 4 + r);
#pragma unroll
          for (int dt = 0; dt < 8; ++dt)
#pragma unroll
            for (int r = 0; r < 4; ++r) oa[qi][dt][r] *= scb[r];
        }
        float ts = 0.f;
#pragma unroll
        for (int ktc = 0; ktc < 4; ++ktc)
#pragma unroll
          for (int r = 0; r < 4; ++r) {
            float e = __expf(p[ktc][r] - mn);
            p[ktc][r] = e;
            ts += e;
          }
        ts += __shfl_xor(ts, 16);
        ts += __shfl_xor(ts, 32);
        lr[qi] += ts;
        char* pq = pw + (qi * 16 + la) * 128;
#pragma unroll
        for (int ktc = 0; ktc < 4; ++ktc) {
          uint2 gv;
          gv.x = pack2bf(p[ktc][0], p[ktc][1]);
          gv.y = pack2bf(p[ktc][2], p[ktc][3]);
          *(uint2*)(pq + ((32 * ktc + 8 * lk) ^ ((la & 7) << 4))) = gv;
        }
      }
      asm volatile("s_waitcnt lgkmcnt(0)" ::: "memory");

      bf16x8_t pf[2][2];
#pragma unroll
      for (int qi = 0; qi < 2; ++qi)
#pragma unroll
        for (int ks = 0; ks < 2; ++ks)
          pf[qi][ks] = __builtin_bit_cast(
              bf16x8_t, *(const ushort8*)(pw + (qi * 16 + la) * 128 +
                                          ((64 * ks + 16 * lk) ^ ((la & 7) << 4))));
      __builtin_amdgcn_s_setprio(1);
#pragma unroll
      for (int dt = 0; dt < 8; ++dt) {
        int d = dt * 16 + la;
#pragma unroll
        for (int ks = 0; ks < 2; ++ks) {
          bf16x8_t vf = __builtin_bit_cast(
              bf16x8_t, *(const ushort8*)(Vsb + d * 128 + ((((ks << 2) + lk) ^ (d & 7)) << 4)));
          oa[0][dt] = __builtin_amdgcn_mfma_f32_16x16x32_bf16(pf[0][ks], vf, oa[0][dt], 0, 0, 0);
          oa[1][dt] = __builtin_amdgcn_mfma_f32_16x16x32_bf16(pf[1][ks], vf, oa[1][dt], 0, 0, 0);
        }
      }
      __builtin_amdgcn_s_setprio(0);
    }

    __syncthreads();           // all waves done reading K/V LDS
    if (kt + 1 < kte) {
      WRITEL();                // compiler inserts vmcnt waits for the staged loads
      __syncthreads();         // staged tile visible to all
    }
  }

  if (full) {
#pragma unroll
    for (int qi = 0; qi < 2; ++qi) {
      float inv = 1.f / lr[qi];
      float invb[4];
#pragma unroll
      for (int r = 0; r < 4; ++r) invb[r] = __shfl(inv, lk * 4 + r);
#pragma unroll
      for (int dt = 0; dt < 8; ++dt)
#pragma unroll
        for (int r = 0; r < 4; ++r)
          Ob[(size_t)(b * S + qw + qi * 16 + lk * 4 + r) * 2048 + h * 128 + dt * 16 + la] =
              f2bf(oa[qi][dt][r] * invb[r]);
    }
  } else {
    const int slot = (b * 16 + h) * 8 + (qt - 8);
    unsigned short* op = oP + ((size_t)slot * 2 + c) * (128 * 128);
    float* ml = mlP + ((size_t)slot * 2 + c) * 256;
#pragma unroll
    for (int qi = 0; qi < 2; ++qi) {
      if (lk == 0) {
        ml[w * 32 + qi * 16 + la] = mr[qi];
        ml[128 + w * 32 + qi * 16 + la] = lr[qi];
      }
      float inv = 1.f / lr[qi];
      float invb[4];
#pragma unroll
      for (int r = 0; r < 4; ++r) invb[r] = __shfl(inv, lk * 4 + r);
#pragma unroll
      for (int dt = 0; dt < 8; ++dt)
#pragma unroll
        for (int r = 0; r < 4; ++r)
          op[(size_t)(w * 32 + qi * 16 + lk * 4 + r) * 128 + dt * 16 + la] =
              f2bf(oa[qi][dt][r] * invb[r]);
    }
  }
#undef LOADR
#undef WRITEL
}

// ---------- combine partial attention outputs (qt >= 8) ----------
__global__ __launch_bounds__(256) void combine_k(const unsigned short* __restrict__ oP,
                                                 const float* __restrict__ mlP,
                                                 unsigned short* __restrict__ Ob) {
  const int slot = blockIdx.x;  // ((b*16+h)*8 + qt-8)
  const int b = slot >> 7, h = (slot >> 3) & 15, qt = 8 + (slot & 7);
  const int t = threadIdx.x;
  const int r = t >> 1, half = t & 1;
  const float* ml0 = mlP + (size_t)slot * 512;
  const float* ml1 = ml0 + 256;
  float m0 = ml0[r], l0 = ml0[128 + r], m1 = ml1[r], l1 = ml1[128 + r];
  float M = fmaxf(m0, m1);
  float w0 = l0 * __expf(m0 - M), w1 = l1 * __expf(m1 - M);
  float inv = 1.f / (w0 + w1);
  w0 *= inv;
  w1 *= inv;
  const unsigned short* o0 = oP + (size_t)slot * 2 * 16384 + r * 128 + half * 64;
  const unsigned short* o1 = o0 + 16384;
  unsigned short* ob = Ob + (size_t)(b * 2048 + qt * 128 + r) * 2048 + h * 128 + half * 64;
#pragma unroll
  for (int j = 0; j < 64; j += 8) {
    ushort8 a = *(const ushort8*)(o0 + j);
    ushort8 c = *(const ushort8*)(o1 + j);
    ushort8 o;
#pragma unroll
    for (int e = 0; e < 8; ++e) o[e] = f2bf(w0 * b2f(a[e]) + w1 * b2f(c[e]));
    *(ushort8*)(ob + j) = o;
  }
}

extern "C" void kernel_launch(void* const* d_in, const int* in_sizes, int n_in,
                              void* d_out, int out_size, void* d_ws, size_t ws_size,
                              hipStream_t stream) {
  const float* x = (const float*)d_in[0];
  const float* rc = (const float*)d_in[1];
  const float* rs = (const float*)d_in[2];
  const float* Wq = (const float*)d_in[3];
  const float* Wk = (const float*)d_in[4];
  const float* Wv = (const float*)d_in[5];
  const float* Wo = (const float*)d_in[6];
  float* out = (float*)d_out;

  const int B = 2, S = 2048, DM = 2048;
  const int M = B * S;  // 4096

  // workspace (bf16 elems): xb | QKV | WallT (later WoT + Vt) | oP | mlP
  unsigned short* xb = (unsigned short*)d_ws;              // M x 2048      (16 MB)
  unsigned short* QKV = xb + (size_t)M * DM;               // M x 3072      (25.2 MB)
  unsigned short* WallT = QKV + (size_t)M * 3072;          // 3072 x 2048   (12.6 MB)
  unsigned short* WoT = WallT;                             // alias (after QKV proj)
  unsigned short* Vt = WallT + (size_t)2048 * 2048;        // 1024 x 2048 (4 MB, dead Wk/Wv rows)
  unsigned short* Ob = xb;                                 // alias (x dead after proj)
  unsigned short* oP = WallT + (size_t)3072 * 2048;        // 256 slots x 2 x 128 x 128 (16 MB)
  float* mlP = (float*)(oP + (size_t)256 * 2 * 16384);     // 256 x 2 x 256 fp32 (0.5 MB)

  dim3 blk(256);

  // prepass
  cvt_k<<<(M * DM / 8 + 255) / 256, blk, 0, stream>>>(x, xb, M * DM / 8);
  twc_k<<<dim3(64, 64), dim3(32, 8), 0, stream>>>(Wq, WallT, DM, DM);
  twc_k<<<dim3(64, 16), dim3(32, 8), 0, stream>>>(Wk, WallT + (size_t)2048 * DM, DM, 512);
  twc_k<<<dim3(64, 16), dim3(32, 8), 0, stream>>>(Wv, WallT + (size_t)2560 * DM, DM, 512);

  // fused QKV projection + RoPE on cols < 2560 (Q and K regions)
  gemm_tn<true, true><<<dim3(3072 / 128, M / 128), blk, 0, stream>>>(xb, WallT, QKV, M, 3072, DM,
                                                                     rc, rs, 2560);

  // Wo transpose (overwrites WallT rows 0..2047)
  twc_k<<<dim3(64, 64), dim3(32, 8), 0, stream>>>(Wo, WoT, DM, DM);

  transpose_v<<<dim3(S / 32, 4, B * 4), dim3(32, 8), 0, stream>>>(QKV, Vt);

  attn_mfma<<<dim3(24, 16, B), blk, 0, stream>>>(QKV, Vt, Ob, oP, mlP);
  combine_k<<<dim3(256), blk, 0, stream>>>(oP, mlP, Ob);

  gemm_tn<false, false><<<dim3(DM / 128, M / 128), blk, 0, stream>>>(Ob, WoT, out, M, DM, DM,
                                                                     nullptr, nullptr, 0);
}

// Round 16
// 265.903 us; speedup vs baseline: 1.3846x; 1.3846x over previous
//
#include <hip/hip_runtime.h>
#include <hip/hip_bf16.h>
#include <math.h>

typedef __bf16 bf16x8_t __attribute__((ext_vector_type(8)));
typedef float f32x4 __attribute__((ext_vector_type(4)));
typedef unsigned short ushort8 __attribute__((ext_vector_type(8)));

__device__ inline unsigned short f2bf(float f) {
  unsigned int u = __builtin_bit_cast(unsigned int, f);
  u += 0x7fffu + ((u >> 16) & 1u);
  return (unsigned short)(u >> 16);
}
__device__ inline float b2f(unsigned short s) {
  unsigned int u = ((unsigned int)s) << 16;
  return __builtin_bit_cast(float, u);
}
__device__ inline unsigned int pack2bf(float lo, float hi) {
  return (unsigned int)f2bf(lo) | ((unsigned int)f2bf(hi) << 16);
}

__device__ __forceinline__ void gll16(const void* g, void* l) {
  __builtin_amdgcn_global_load_lds((const __attribute__((address_space(1))) void*)g,
                                   (__attribute__((address_space(3))) void*)l, 16, 0, 0);
}

// ---------- prepass: fp32 -> bf16 convert ----------
__global__ void cvt_k(const float* __restrict__ X, unsigned short* __restrict__ Xb, int total8) {
  int i = blockIdx.x * blockDim.x + threadIdx.x;
  if (i >= total8) return;
  const float4* p = (const float4*)X + 2 * (size_t)i;
  float4 a = p[0], b = p[1];
  ushort8 v;
  v[0] = f2bf(a.x); v[1] = f2bf(a.y); v[2] = f2bf(a.z); v[3] = f2bf(a.w);
  v[4] = f2bf(b.x); v[5] = f2bf(b.y); v[6] = f2bf(b.z); v[7] = f2bf(b.w);
  ((ushort8*)Xb)[i] = v;
}

// ---------- prepass: transpose + convert: Wt[n][k] = bf16(W[k][n]) ----------
__global__ void twc_k(const float* __restrict__ W, unsigned short* __restrict__ Wt, int K, int N) {
  __shared__ float tile[32][33];
  int k0 = blockIdx.x * 32, n0 = blockIdx.y * 32;
  int tx = threadIdx.x, ty = threadIdx.y;  // 32 x 8
#pragma unroll
  for (int i = 0; i < 32; i += 8) tile[ty + i][tx] = W[(size_t)(k0 + ty + i) * N + n0 + tx];
  __syncthreads();
#pragma unroll
  for (int i = 0; i < 32; i += 8)
    Wt[(size_t)(n0 + ty + i) * K + k0 + tx] = f2bf(tile[tx][ty + i]);
}

// ---------- 2-phase pipelined GEMM: C[M][N] = A[M][K] @ Bt[N][K]^T, optional fused RoPE ----------
template <bool OUT_BF16, bool ROPE>
__global__ __launch_bounds__(256) void gemm_tn(const unsigned short* __restrict__ A,
                                               const unsigned short* __restrict__ Bt,
                                               void* __restrict__ Cv, int M, int N, int K,
                                               const float* __restrict__ cs,
                                               const float* __restrict__ sn, int ropeLim) {
  __shared__ __align__(16) unsigned short As[2][128 * 32];
  __shared__ __align__(16) unsigned short Bs[2][128 * 32];
  const int t = threadIdx.x, w = t >> 6, lane = t & 63;
  const int la = lane & 15, lk = lane >> 4;
  const int wr = w >> 1, wc = w & 1;
  const int bm = blockIdx.y * 128, bn = blockIdx.x * 128;
  const int lrow = lane >> 2, lcb = (lane & 3) * 8;

  const unsigned short* Ab = A + (size_t)(bm + (w * 2) * 16 + lrow) * K + lcb;
  const unsigned short* Ab1 = A + (size_t)(bm + (w * 2 + 1) * 16 + lrow) * K + lcb;
  const unsigned short* Bb = Bt + (size_t)(bn + (w * 2) * 16 + lrow) * K + lcb;
  const unsigned short* Bb1 = Bt + (size_t)(bn + (w * 2 + 1) * 16 + lrow) * K + lcb;
  const int c0 = w * 2, c1 = w * 2 + 1;

  f32x4 acc[4][4] = {};

  gll16(Ab, (char*)As[0] + c0 * 1024);
  gll16(Ab1, (char*)As[0] + c1 * 1024);
  gll16(Bb, (char*)Bs[0] + c0 * 1024);
  gll16(Bb1, (char*)Bs[0] + c1 * 1024);

  const int nt = K / 32;
  int cur = 0;
  for (int kt = 0; kt < nt; ++kt) {
    __syncthreads();
    if (kt + 1 < nt) {
      const int kn = (kt + 1) * 32;
      gll16(Ab + kn, (char*)As[cur ^ 1] + c0 * 1024);
      gll16(Ab1 + kn, (char*)As[cur ^ 1] + c1 * 1024);
      gll16(Bb + kn, (char*)Bs[cur ^ 1] + c0 * 1024);
      gll16(Bb1 + kn, (char*)Bs[cur ^ 1] + c1 * 1024);
    }

    bf16x8_t a[4], b[4];
#pragma unroll
    for (int m = 0; m < 4; ++m)
      a[m] = __builtin_bit_cast(
          bf16x8_t, *(const ushort8*)(As[cur] + (wr * 64 + m * 16 + la) * 32 + lk * 8));
#pragma unroll
    for (int n = 0; n < 4; ++n)
      b[n] = __builtin_bit_cast(
          bf16x8_t, *(const ushort8*)(Bs[cur] + (wc * 64 + n * 16 + la) * 32 + lk * 8));
#pragma unroll
    for (int m = 0; m < 4; ++m)
#pragma unroll
      for (int n = 0; n < 4; ++n)
        acc[m][n] = __builtin_amdgcn_mfma_f32_16x16x32_bf16(a[m], b[n], acc[m][n], 0, 0, 0);
    cur ^= 1;
  }

#pragma unroll
  for (int m = 0; m < 4; ++m) {
#pragma unroll
    for (int n = 0; n < 4; ++n) {
      const int col = bn + wc * 64 + n * 16 + la;
      const bool doRope = ROPE && (col < ropeLim);
#pragma unroll
      for (int r = 0; r < 4; ++r) {
        int row = bm + wr * 64 + m * 16 + lk * 4 + r;
        float val = acc[m][n][r];
        if (ROPE) {
          float pval = __shfl_xor(val, 1);
          if (doRope) {
            int srow = row & 2047;
            int i = (col & 127) >> 1;
            float cc = cs[srow * 64 + i], ss = sn[srow * 64 + i];
            val = (la & 1) ? (pval * ss + val * cc) : (val * cc - pval * ss);
          }
        }
        if (OUT_BF16)
          ((unsigned short*)Cv)[(size_t)row * N + col] = f2bf(val);
        else
          ((float*)Cv)[(size_t)row * N + col] = val;
      }
    }
  }
}

// ---------- V transpose: Vt[(b*4+g)*128 + d][s] = QKV[(b*2048+s)*3072 + 2560 + g*128 + d] ----------
__global__ void transpose_v(const unsigned short* __restrict__ QKV, unsigned short* __restrict__ Vt) {
  __shared__ unsigned short tile[32][33];
  int bg = blockIdx.z;
  int b = bg >> 2, g = bg & 3;
  int s0 = blockIdx.x * 32, d0 = blockIdx.y * 32;
  int tx = threadIdx.x, ty = threadIdx.y;  // 32 x 8
#pragma unroll
  for (int i = 0; i < 32; i += 8)
    tile[ty + i][tx] = QKV[((size_t)(b * 2048 + s0 + ty + i)) * 3072 + 2560 + g * 128 + d0 + tx];
  __syncthreads();
#pragma unroll
  for (int i = 0; i < 32; i += 8)
    Vt[((size_t)(bg * 128 + d0 + ty + i)) * 2048 + s0 + tx] = tile[tx][ty + i];
}

// ---------- MFMA flash attention: kv-split + gll16 double-buffer (R14 staging, R15 split) ----------
// 4 waves x 32 q-rows, kv-tile 64, swapped QK^T, packed-P LDS, defer-max.
// grid (24, 16, B): x -> (qt, chunk) heavy-first. Chunks: c0 = kv[0,1024), c1 = kv[1024, qend).
// Partial blocks (qt>=8) emit normalized O (bf16) + (m,l); combine_k merges.
__global__ __launch_bounds__(256, 2) void attn_mfma(const unsigned short* __restrict__ QKV,
                                                    const unsigned short* __restrict__ Vt,
                                                    unsigned short* __restrict__ Ob,
                                                    unsigned short* __restrict__ oP,
                                                    float* __restrict__ mlP) {
  const int S = 2048;
  __shared__ __align__(16) unsigned short Ks[2][64 * 128];   // linear [krow][d], pre-swizzled
  __shared__ __align__(16) unsigned short Vs[2][128 * 64];   // linear [d][kv], pre-swizzled
  __shared__ __align__(16) unsigned short Ps[4 * 32 * 64];   // per-wave packed P

  const int t = threadIdx.x;
  const int w = t >> 6, lane = t & 63;
  const int la = lane & 15, lk = lane >> 4;
  const int b = blockIdx.z, h = blockIdx.y, g = h >> 2;

  // x -> (qt, c), heavy-first
  int x = blockIdx.x, qt, c;
  if (x < 9) { qt = 7 + x; c = 0; }
  else if (x == 9) { qt = 15; c = 1; }
  else { int k = (x - 10) >> 1; if ((x & 1) == 0) { qt = 6 - k; c = 0; } else { qt = 14 - k; c = 1; } }

  const int qw = qt * 128 + w * 32;
  const int n_full = 2 * qt + 2;
  const int kts = c * 16;
  const int kte = min(n_full, kts + 16);
  const bool full = (kts == 0) && (kte == n_full);
  const float scale = 0.08838834764831845f;  // 1/sqrt(128)

  // staging: wave w stages K groups 4w..4w+3 (4 rows x 16 chunks) and V groups (8 rows x 8 chunks)
  // pre-swizzled GLOBAL source, linear LDS dest (m173 pattern)
  const unsigned short* ksrc[4];
  const unsigned short* vsrc[4];
#pragma unroll
  for (int u = 0; u < 4; ++u) {
    int kr = 16 * w + 4 * u + (lane >> 4);
    int kp = lane & 15;
    ksrc[u] = QKV + (size_t)(b * S + kr) * 3072 + 2048 + g * 128 + (kp ^ (kr & 7)) * 8;
    int vr = 32 * w + 8 * u + (lane >> 3);
    int vp = lane & 7;
    vsrc[u] = Vt + (size_t)((b * 4 + g) * 128 + vr) * 2048 + (vp ^ (vr & 7)) * 8;
  }

  // Q fragments
  bf16x8_t qf[2][4];
#pragma unroll
  for (int qi = 0; qi < 2; ++qi)
#pragma unroll
    for (int dt = 0; dt < 4; ++dt)
      qf[qi][dt] = __builtin_bit_cast(
          bf16x8_t, *(const ushort8*)(QKV + (size_t)(b * S + qw + qi * 16 + la) * 3072 + h * 128 +
                                      dt * 32 + lk * 8));

  f32x4 oa[2][8];
#pragma unroll
  for (int qi = 0; qi < 2; ++qi)
#pragma unroll
    for (int dt = 0; dt < 8; ++dt) oa[qi][dt] = (f32x4){0.f, 0.f, 0.f, 0.f};
  float mr[2] = {-1e30f, -1e30f}, lr[2] = {0.f, 0.f};

  const int kmask0 = qw & ~63;
  char* pw = (char*)Ps + w * 4096;

  // prologue: stage tile kts into buf 0
#pragma unroll
  for (int u = 0; u < 4; ++u) {
    gll16(ksrc[u] + (size_t)(kts * 64) * 3072, (char*)Ks[0] + (4 * w + u) * 1024);
    gll16(vsrc[u] + kts * 64, (char*)Vs[0] + (4 * w + u) * 1024);
  }
  __syncthreads();

  int cur = 0;
  for (int kt = kts; kt < kte; ++kt) {
    const int k0 = kt * 64;
    // prefetch next tile into the other buffer
    if (kt + 1 < kte) {
      const int kn = k0 + 64;
#pragma unroll
      for (int u = 0; u < 4; ++u) {
        gll16(ksrc[u] + (size_t)kn * 3072, (char*)Ks[cur ^ 1] + (4 * w + u) * 1024);
        gll16(vsrc[u] + kn, (char*)Vs[cur ^ 1] + (4 * w + u) * 1024);
      }
    }

    if (k0 <= qw + 31) {  // wave not fully masked
      char* Ksb = (char*)Ks[cur];
      char* Vsb = (char*)Vs[cur];

      // swapped QK^T: sacc[qi][ktc] = S^T tile: row = kv (lk*4+r within ktc), col = q (la)
      f32x4 sacc[2][4];
#pragma unroll
      for (int qi = 0; qi < 2; ++qi)
#pragma unroll
        for (int ktc = 0; ktc < 4; ++ktc) sacc[qi][ktc] = (f32x4){0.f, 0.f, 0.f, 0.f};
      __builtin_amdgcn_s_setprio(1);
#pragma unroll
      for (int ktc = 0; ktc < 4; ++ktc) {
        int row = ktc * 16 + la;
#pragma unroll
        for (int dt = 0; dt < 4; ++dt) {
          bf16x8_t kf = __builtin_bit_cast(
              bf16x8_t, *(const ushort8*)(Ksb + row * 256 + ((((dt << 2) + lk) ^ (row & 7)) << 4)));
          sacc[0][ktc] = __builtin_amdgcn_mfma_f32_16x16x32_bf16(kf, qf[0][dt], sacc[0][ktc], 0, 0, 0);
          sacc[1][ktc] = __builtin_amdgcn_mfma_f32_16x16x32_bf16(kf, qf[1][dt], sacc[1][ktc], 0, 0, 0);
        }
      }
      __builtin_amdgcn_s_setprio(0);

      const bool domask = (k0 == kmask0);
#pragma unroll
      for (int qi = 0; qi < 2; ++qi) {
        const int q = qw + qi * 16 + la;  // this lane's softmax row
        float p[4][4];
        float tm = -1e30f;
#pragma unroll
        for (int ktc = 0; ktc < 4; ++ktc)
#pragma unroll
          for (int r = 0; r < 4; ++r) {
            float sv = sacc[qi][ktc][r] * scale;
            if (domask && (k0 + ktc * 16 + lk * 4 + r > q)) sv = -1e30f;
            p[ktc][r] = sv;
            tm = fmaxf(tm, sv);
          }
        tm = fmaxf(tm, __shfl_xor(tm, 16));
        tm = fmaxf(tm, __shfl_xor(tm, 32));
        // defer-max (T13)
        float mn;
        if (__all(tm - mr[qi] <= 8.f)) {
          mn = mr[qi];
        } else {
          mn = fmaxf(mr[qi], tm);
          float sc = __expf(mr[qi] - mn);
          mr[qi] = mn;
          lr[qi] *= sc;
          float scb[4];
#pragma unroll
          for (int r = 0; r < 4; ++r) scb[r] = __shfl(sc, lk * 4 + r);
#pragma unroll
          for (int dt = 0; dt < 8; ++dt)
#pragma unroll
            for (int r = 0; r < 4; ++r) oa[qi][dt][r] *= scb[r];
        }
        float ts = 0.f;
#pragma unroll
        for (int ktc = 0; ktc < 4; ++ktc)
#pragma unroll
          for (int r = 0; r < 4; ++r) {
            float e = __expf(p[ktc][r] - mn);
            p[ktc][r] = e;
            ts += e;
          }
        ts += __shfl_xor(ts, 16);
        ts += __shfl_xor(ts, 32);
        lr[qi] += ts;
        // packed P write (b64, swizzled, per-wave)
        char* pq = pw + (qi * 16 + la) * 128;
#pragma unroll
        for (int ktc = 0; ktc < 4; ++ktc) {
          uint2 gv;
          gv.x = pack2bf(p[ktc][0], p[ktc][1]);
          gv.y = pack2bf(p[ktc][2], p[ktc][3]);
          *(uint2*)(pq + ((32 * ktc + 8 * lk) ^ ((la & 7) << 4))) = gv;
        }
      }
      asm volatile("s_waitcnt lgkmcnt(0)" ::: "memory");

      // P fragments
      bf16x8_t pf[2][2];
#pragma unroll
      for (int qi = 0; qi < 2; ++qi)
#pragma unroll
        for (int ks = 0; ks < 2; ++ks)
          pf[qi][ks] = __builtin_bit_cast(
              bf16x8_t, *(const ushort8*)(pw + (qi * 16 + la) * 128 +
                                          ((64 * ks + 16 * lk) ^ ((la & 7) << 4))));
      __builtin_amdgcn_s_setprio(1);
#pragma unroll
      for (int dt = 0; dt < 8; ++dt) {
        int d = dt * 16 + la;
#pragma unroll
        for (int ks = 0; ks < 2; ++ks) {
          bf16x8_t vf = __builtin_bit_cast(
              bf16x8_t, *(const ushort8*)(Vsb + d * 128 + ((((ks << 2) + lk) ^ (d & 7)) << 4)));
          oa[0][dt] = __builtin_amdgcn_mfma_f32_16x16x32_bf16(pf[0][ks], vf, oa[0][dt], 0, 0, 0);
          oa[1][dt] = __builtin_amdgcn_mfma_f32_16x16x32_bf16(pf[1][ks], vf, oa[1][dt], 0, 0, 0);
        }
      }
      __builtin_amdgcn_s_setprio(0);
    }

    __syncthreads();  // prefetched tile landed; all reads of cur done
    cur ^= 1;
  }

  if (full) {
#pragma unroll
    for (int qi = 0; qi < 2; ++qi) {
      float inv = 1.f / lr[qi];
      float invb[4];
#pragma unroll
      for (int r = 0; r < 4; ++r) invb[r] = __shfl(inv, lk * 4 + r);
#pragma unroll
      for (int dt = 0; dt < 8; ++dt)
#pragma unroll
        for (int r = 0; r < 4; ++r)
          Ob[(size_t)(b * S + qw + qi * 16 + lk * 4 + r) * 2048 + h * 128 + dt * 16 + la] =
              f2bf(oa[qi][dt][r] * invb[r]);
    }
  } else {
    const int slot = (b * 16 + h) * 8 + (qt - 8);
    unsigned short* op = oP + ((size_t)slot * 2 + c) * (128 * 128);
    float* ml = mlP + ((size_t)slot * 2 + c) * 256;
#pragma unroll
    for (int qi = 0; qi < 2; ++qi) {
      if (lk == 0) {
        ml[w * 32 + qi * 16 + la] = mr[qi];
        ml[128 + w * 32 + qi * 16 + la] = lr[qi];
      }
      float inv = 1.f / lr[qi];
      float invb[4];
#pragma unroll
      for (int r = 0; r < 4; ++r) invb[r] = __shfl(inv, lk * 4 + r);
#pragma unroll
      for (int dt = 0; dt < 8; ++dt)
#pragma unroll
        for (int r = 0; r < 4; ++r)
          op[(size_t)(w * 32 + qi * 16 + lk * 4 + r) * 128 + dt * 16 + la] =
              f2bf(oa[qi][dt][r] * invb[r]);
    }
  }
}

// ---------- combine partial attention outputs (qt >= 8) ----------
__global__ __launch_bounds__(256) void combine_k(const unsigned short* __restrict__ oP,
                                                 const float* __restrict__ mlP,
                                                 unsigned short* __restrict__ Ob) {
  const int slot = blockIdx.x;  // ((b*16+h)*8 + qt-8)
  const int b = slot >> 7, h = (slot >> 3) & 15, qt = 8 + (slot & 7);
  const int t = threadIdx.x;
  const int r = t >> 1, half = t & 1;
  const float* ml0 = mlP + (size_t)slot * 512;
  const float* ml1 = ml0 + 256;
  float m0 = ml0[r], l0 = ml0[128 + r], m1 = ml1[r], l1 = ml1[128 + r];
  float M = fmaxf(m0, m1);
  float w0 = l0 * __expf(m0 - M), w1 = l1 * __expf(m1 - M);
  float inv = 1.f / (w0 + w1);
  w0 *= inv;
  w1 *= inv;
  const unsigned short* o0 = oP + (size_t)slot * 2 * 16384 + r * 128 + half * 64;
  const unsigned short* o1 = o0 + 16384;
  unsigned short* ob = Ob + (size_t)(b * 2048 + qt * 128 + r) * 2048 + h * 128 + half * 64;
#pragma unroll
  for (int j = 0; j < 64; j += 8) {
    ushort8 a = *(const ushort8*)(o0 + j);
    ushort8 c = *(const ushort8*)(o1 + j);
    ushort8 o;
#pragma unroll
    for (int e = 0; e < 8; ++e) o[e] = f2bf(w0 * b2f(a[e]) + w1 * b2f(c[e]));
    *(ushort8*)(ob + j) = o;
  }
}

extern "C" void kernel_launch(void* const* d_in, const int* in_sizes, int n_in,
                              void* d_out, int out_size, void* d_ws, size_t ws_size,
                              hipStream_t stream) {
  const float* x = (const float*)d_in[0];
  const float* rc = (const float*)d_in[1];
  const float* rs = (const float*)d_in[2];
  const float* Wq = (const float*)d_in[3];
  const float* Wk = (const float*)d_in[4];
  const float* Wv = (const float*)d_in[5];
  const float* Wo = (const float*)d_in[6];
  float* out = (float*)d_out;

  const int B = 2, S = 2048, DM = 2048;
  const int M = B * S;  // 4096

  // workspace (bf16 elems): xb | QKV | WallT (later WoT + Vt) | oP | mlP
  unsigned short* xb = (unsigned short*)d_ws;              // M x 2048      (16 MB)
  unsigned short* QKV = xb + (size_t)M * DM;               // M x 3072      (25.2 MB)
  unsigned short* WallT = QKV + (size_t)M * 3072;          // 3072 x 2048   (12.6 MB)
  unsigned short* WoT = WallT;                             // alias (after QKV proj)
  unsigned short* Vt = WallT + (size_t)2048 * 2048;        // 1024 x 2048 (4 MB, dead Wk/Wv rows)
  unsigned short* Ob = xb;                                 // alias (x dead after proj)
  unsigned short* oP = WallT + (size_t)3072 * 2048;        // 256 slots x 2 x 128 x 128 (16 MB)
  float* mlP = (float*)(oP + (size_t)256 * 2 * 16384);     // 256 x 2 x 256 fp32 (0.5 MB)

  dim3 blk(256);

  // prepass
  cvt_k<<<(M * DM / 8 + 255) / 256, blk, 0, stream>>>(x, xb, M * DM / 8);
  twc_k<<<dim3(64, 64), dim3(32, 8), 0, stream>>>(Wq, WallT, DM, DM);
  twc_k<<<dim3(64, 16), dim3(32, 8), 0, stream>>>(Wk, WallT + (size_t)2048 * DM, DM, 512);
  twc_k<<<dim3(64, 16), dim3(32, 8), 0, stream>>>(Wv, WallT + (size_t)2560 * DM, DM, 512);

  // fused QKV projection + RoPE on cols < 2560 (Q and K regions)
  gemm_tn<true, true><<<dim3(3072 / 128, M / 128), blk, 0, stream>>>(xb, WallT, QKV, M, 3072, DM,
                                                                     rc, rs, 2560);

  // Wo transpose (overwrites WallT rows 0..2047)
  twc_k<<<dim3(64, 64), dim3(32, 8), 0, stream>>>(Wo, WoT, DM, DM);

  transpose_v<<<dim3(S / 32, 4, B * 4), dim3(32, 8), 0, stream>>>(QKV, Vt);

  attn_mfma<<<dim3(24, 16, B), blk, 0, stream>>>(QKV, Vt, Ob, oP, mlP);
  combine_k<<<dim3(256), blk, 0, stream>>>(oP, mlP, Ob);

  gemm_tn<false, false><<<dim3(DM / 128, M / 128), blk, 0, stream>>>(Ob, WoT, out, M, DM, DM,
                                                                     nullptr, nullptr, 0);
}

// Round 17
// 261.348 us; speedup vs baseline: 1.4088x; 1.0174x over previous
//
#include <hip/hip_runtime.h>
#include <hip/hip_bf16.h>
#include <math.h>

typedef __bf16 bf16x8_t __attribute__((ext_vector_type(8)));
typedef float f32x4 __attribute__((ext_vector_type(4)));
typedef unsigned short ushort8 __attribute__((ext_vector_type(8)));

__device__ inline unsigned short f2bf(float f) {
  unsigned int u = __builtin_bit_cast(unsigned int, f);
  u += 0x7fffu + ((u >> 16) & 1u);
  return (unsigned short)(u >> 16);
}
__device__ inline float b2f(unsigned short s) {
  unsigned int u = ((unsigned int)s) << 16;
  return __builtin_bit_cast(float, u);
}
__device__ inline unsigned int pack2bf(float lo, float hi) {
  return (unsigned int)f2bf(lo) | ((unsigned int)f2bf(hi) << 16);
}

__device__ __forceinline__ void gll16(const void* g, void* l) {
  __builtin_amdgcn_global_load_lds((const __attribute__((address_space(1))) void*)g,
                                   (__attribute__((address_space(3))) void*)l, 16, 0, 0);
}

// ---------- prepass: fp32 -> bf16 convert ----------
__global__ void cvt_k(const float* __restrict__ X, unsigned short* __restrict__ Xb, int total8) {
  int i = blockIdx.x * blockDim.x + threadIdx.x;
  if (i >= total8) return;
  const float4* p = (const float4*)X + 2 * (size_t)i;
  float4 a = p[0], b = p[1];
  ushort8 v;
  v[0] = f2bf(a.x); v[1] = f2bf(a.y); v[2] = f2bf(a.z); v[3] = f2bf(a.w);
  v[4] = f2bf(b.x); v[5] = f2bf(b.y); v[6] = f2bf(b.z); v[7] = f2bf(b.w);
  ((ushort8*)Xb)[i] = v;
}

// ---------- prepass: transpose + convert: Wt[n][k] = bf16(W[k][n]) ----------
__global__ void twc_k(const float* __restrict__ W, unsigned short* __restrict__ Wt, int K, int N) {
  __shared__ float tile[32][33];
  int k0 = blockIdx.x * 32, n0 = blockIdx.y * 32;
  int tx = threadIdx.x, ty = threadIdx.y;  // 32 x 8
#pragma unroll
  for (int i = 0; i < 32; i += 8) tile[ty + i][tx] = W[(size_t)(k0 + ty + i) * N + n0 + tx];
  __syncthreads();
#pragma unroll
  for (int i = 0; i < 32; i += 8)
    Wt[(size_t)(n0 + ty + i) * K + k0 + tx] = f2bf(tile[tx][ty + i]);
}

// ---------- 2-phase pipelined GEMM: C[M][N] = A[M][K] @ Bt[N][K]^T, optional fused RoPE ----------
template <bool OUT_BF16, bool ROPE>
__global__ __launch_bounds__(256) void gemm_tn(const unsigned short* __restrict__ A,
                                               const unsigned short* __restrict__ Bt,
                                               void* __restrict__ Cv, int M, int N, int K,
                                               const float* __restrict__ cs,
                                               const float* __restrict__ sn, int ropeLim) {
  __shared__ __align__(16) unsigned short As[2][128 * 32];
  __shared__ __align__(16) unsigned short Bs[2][128 * 32];
  const int t = threadIdx.x, w = t >> 6, lane = t & 63;
  const int la = lane & 15, lk = lane >> 4;
  const int wr = w >> 1, wc = w & 1;
  const int bm = blockIdx.y * 128, bn = blockIdx.x * 128;
  const int lrow = lane >> 2, lcb = (lane & 3) * 8;

  const unsigned short* Ab = A + (size_t)(bm + (w * 2) * 16 + lrow) * K + lcb;
  const unsigned short* Ab1 = A + (size_t)(bm + (w * 2 + 1) * 16 + lrow) * K + lcb;
  const unsigned short* Bb = Bt + (size_t)(bn + (w * 2) * 16 + lrow) * K + lcb;
  const unsigned short* Bb1 = Bt + (size_t)(bn + (w * 2 + 1) * 16 + lrow) * K + lcb;
  const int c0 = w * 2, c1 = w * 2 + 1;

  f32x4 acc[4][4] = {};

  gll16(Ab, (char*)As[0] + c0 * 1024);
  gll16(Ab1, (char*)As[0] + c1 * 1024);
  gll16(Bb, (char*)Bs[0] + c0 * 1024);
  gll16(Bb1, (char*)Bs[0] + c1 * 1024);

  const int nt = K / 32;
  int cur = 0;
  for (int kt = 0; kt < nt; ++kt) {
    __syncthreads();
    if (kt + 1 < nt) {
      const int kn = (kt + 1) * 32;
      gll16(Ab + kn, (char*)As[cur ^ 1] + c0 * 1024);
      gll16(Ab1 + kn, (char*)As[cur ^ 1] + c1 * 1024);
      gll16(Bb + kn, (char*)Bs[cur ^ 1] + c0 * 1024);
      gll16(Bb1 + kn, (char*)Bs[cur ^ 1] + c1 * 1024);
    }

    bf16x8_t a[4], b[4];
#pragma unroll
    for (int m = 0; m < 4; ++m)
      a[m] = __builtin_bit_cast(
          bf16x8_t, *(const ushort8*)(As[cur] + (wr * 64 + m * 16 + la) * 32 + lk * 8));
#pragma unroll
    for (int n = 0; n < 4; ++n)
      b[n] = __builtin_bit_cast(
          bf16x8_t, *(const ushort8*)(Bs[cur] + (wc * 64 + n * 16 + la) * 32 + lk * 8));
#pragma unroll
    for (int m = 0; m < 4; ++m)
#pragma unroll
      for (int n = 0; n < 4; ++n)
        acc[m][n] = __builtin_amdgcn_mfma_f32_16x16x32_bf16(a[m], b[n], acc[m][n], 0, 0, 0);
    cur ^= 1;
  }

#pragma unroll
  for (int m = 0; m < 4; ++m) {
#pragma unroll
    for (int n = 0; n < 4; ++n) {
      const int col = bn + wc * 64 + n * 16 + la;
      const bool doRope = ROPE && (col < ropeLim);
#pragma unroll
      for (int r = 0; r < 4; ++r) {
        int row = bm + wr * 64 + m * 16 + lk * 4 + r;
        float val = acc[m][n][r];
        if (ROPE) {
          float pval = __shfl_xor(val, 1);
          if (doRope) {
            int srow = row & 2047;
            int i = (col & 127) >> 1;
            float cc = cs[srow * 64 + i], ss = sn[srow * 64 + i];
            val = (la & 1) ? (pval * ss + val * cc) : (val * cc - pval * ss);
          }
        }
        if (OUT_BF16)
          ((unsigned short*)Cv)[(size_t)row * N + col] = f2bf(val);
        else
          ((float*)Cv)[(size_t)row * N + col] = val;
      }
    }
  }
}

// ---------- V transpose: Vt[(b*4+g)*128 + d][s] = QKV[(b*2048+s)*3072 + 2560 + g*128 + d] ----------
__global__ void transpose_v(const unsigned short* __restrict__ QKV, unsigned short* __restrict__ Vt) {
  __shared__ unsigned short tile[32][33];
  int bg = blockIdx.z;
  int b = bg >> 2, g = bg & 3;
  int s0 = blockIdx.x * 32, d0 = blockIdx.y * 32;
  int tx = threadIdx.x, ty = threadIdx.y;  // 32 x 8
#pragma unroll
  for (int i = 0; i < 32; i += 8)
    tile[ty + i][tx] = QKV[((size_t)(b * 2048 + s0 + ty + i)) * 3072 + 2560 + g * 128 + d0 + tx];
  __syncthreads();
#pragma unroll
  for (int i = 0; i < 32; i += 8)
    Vt[((size_t)(bg * 128 + d0 + ty + i)) * 2048 + s0 + tx] = tile[tx][ty + i];
}

// ---------- MFMA flash attention: kv-split + SINGLE-buffer rotated staging (48 KB -> 3 blocks/CU) ----------
// 4 waves x 32 q-rows, kv-tile 64, swapped QK^T, packed-P LDS, defer-max.
// Pipeline: {QK[t],softmax,P} -> bar1 -> issue K[t+1] -> PV[t] -> bar2 -> issue V[t+1].
// V[t+1] latency hides under QK[t+1]+softmax; K[t+1] under PV[t].
// grid (24, 16, B): x -> (qt, chunk) heavy-first. Partial blocks emit O + (m,l); combine_k merges.
__global__ __launch_bounds__(256, 2) void attn_mfma(const unsigned short* __restrict__ QKV,
                                                    const unsigned short* __restrict__ Vt,
                                                    unsigned short* __restrict__ Ob,
                                                    unsigned short* __restrict__ oP,
                                                    float* __restrict__ mlP) {
  const int S = 2048;
  __shared__ __align__(16) unsigned short Ks[64 * 128];    // 16 KB, linear, data pre-swizzled
  __shared__ __align__(16) unsigned short Vs[128 * 64];    // 16 KB, linear, data pre-swizzled
  __shared__ __align__(16) unsigned short Ps[4 * 32 * 64]; // 16 KB per-wave packed P

  const int t = threadIdx.x;
  const int w = t >> 6, lane = t & 63;
  const int la = lane & 15, lk = lane >> 4;
  const int b = blockIdx.z, h = blockIdx.y, g = h >> 2;

  // x -> (qt, c), heavy-first
  int x = blockIdx.x, qt, c;
  if (x < 9) { qt = 7 + x; c = 0; }
  else if (x == 9) { qt = 15; c = 1; }
  else { int k = (x - 10) >> 1; if ((x & 1) == 0) { qt = 6 - k; c = 0; } else { qt = 14 - k; c = 1; } }

  const int qw = qt * 128 + w * 32;
  const int n_full = 2 * qt + 2;
  const int kts = c * 16;
  const int kte = min(n_full, kts + 16);
  const bool full = (kts == 0) && (kte == n_full);
  const float scale = 0.08838834764831845f;  // 1/sqrt(128)

  // staging: wave w stages K groups 4w..4w+3 (4 rows x 16 chunks) and V groups (8 rows x 8 chunks)
  // pre-swizzled GLOBAL source, linear LDS dest (m173 pattern)
  const unsigned short* ksrc[4];
  const unsigned short* vsrc[4];
#pragma unroll
  for (int u = 0; u < 4; ++u) {
    int kr = 16 * w + 4 * u + (lane >> 4);
    int kp = lane & 15;
    ksrc[u] = QKV + (size_t)(b * S + kr) * 3072 + 2048 + g * 128 + (kp ^ (kr & 7)) * 8;
    int vr = 32 * w + 8 * u + (lane >> 3);
    int vp = lane & 7;
    vsrc[u] = Vt + (size_t)((b * 4 + g) * 128 + vr) * 2048 + (vp ^ (vr & 7)) * 8;
  }

#define STAGE_K(KT)                                                              \
  do {                                                                           \
    const size_t _o = (size_t)(KT) * 64 * 3072;                                  \
    _Pragma("unroll") for (int u = 0; u < 4; ++u)                                \
        gll16(ksrc[u] + _o, (char*)Ks + (4 * w + u) * 1024);                     \
  } while (0)
#define STAGE_V(KT)                                                              \
  do {                                                                           \
    const size_t _o = (size_t)(KT) * 64;                                         \
    _Pragma("unroll") for (int u = 0; u < 4; ++u)                                \
        gll16(vsrc[u] + _o, (char*)Vs + (4 * w + u) * 1024);                     \
  } while (0)

  // Q fragments
  bf16x8_t qf[2][4];
#pragma unroll
  for (int qi = 0; qi < 2; ++qi)
#pragma unroll
    for (int dt = 0; dt < 4; ++dt)
      qf[qi][dt] = __builtin_bit_cast(
          bf16x8_t, *(const ushort8*)(QKV + (size_t)(b * S + qw + qi * 16 + la) * 3072 + h * 128 +
                                      dt * 32 + lk * 8));

  f32x4 oa[2][8];
#pragma unroll
  for (int qi = 0; qi < 2; ++qi)
#pragma unroll
    for (int dt = 0; dt < 8; ++dt) oa[qi][dt] = (f32x4){0.f, 0.f, 0.f, 0.f};
  float mr[2] = {-1e30f, -1e30f}, lr[2] = {0.f, 0.f};

  const int kmask0 = qw & ~63;
  char* pw = (char*)Ps + w * 4096;
  char* Ksb = (char*)Ks;
  char* Vsb = (char*)Vs;

  // prologue: stage first K and V tiles
  STAGE_K(kts);
  STAGE_V(kts);
  __syncthreads();  // drains both

  for (int kt = kts; kt < kte; ++kt) {
    const int k0 = kt * 64;
    const bool active = (k0 <= qw + 31);

    bf16x8_t pf[2][2];
    if (active) {
      // swapped QK^T: row = kv (lk*4+r within ktc), col = q (la)
      f32x4 sacc[2][4];
#pragma unroll
      for (int qi = 0; qi < 2; ++qi)
#pragma unroll
        for (int ktc = 0; ktc < 4; ++ktc) sacc[qi][ktc] = (f32x4){0.f, 0.f, 0.f, 0.f};
      __builtin_amdgcn_s_setprio(1);
#pragma unroll
      for (int ktc = 0; ktc < 4; ++ktc) {
        int row = ktc * 16 + la;
#pragma unroll
        for (int dt = 0; dt < 4; ++dt) {
          bf16x8_t kf = __builtin_bit_cast(
              bf16x8_t, *(const ushort8*)(Ksb + row * 256 + ((((dt << 2) + lk) ^ (row & 7)) << 4)));
          sacc[0][ktc] = __builtin_amdgcn_mfma_f32_16x16x32_bf16(kf, qf[0][dt], sacc[0][ktc], 0, 0, 0);
          sacc[1][ktc] = __builtin_amdgcn_mfma_f32_16x16x32_bf16(kf, qf[1][dt], sacc[1][ktc], 0, 0, 0);
        }
      }
      __builtin_amdgcn_s_setprio(0);

      const bool domask = (k0 == kmask0);
#pragma unroll
      for (int qi = 0; qi < 2; ++qi) {
        const int q = qw + qi * 16 + la;
        float p[4][4];
        float tm = -1e30f;
#pragma unroll
        for (int ktc = 0; ktc < 4; ++ktc)
#pragma unroll
          for (int r = 0; r < 4; ++r) {
            float sv = sacc[qi][ktc][r] * scale;
            if (domask && (k0 + ktc * 16 + lk * 4 + r > q)) sv = -1e30f;
            p[ktc][r] = sv;
            tm = fmaxf(tm, sv);
          }
        tm = fmaxf(tm, __shfl_xor(tm, 16));
        tm = fmaxf(tm, __shfl_xor(tm, 32));
        // defer-max (T13)
        float mn;
        if (__all(tm - mr[qi] <= 8.f)) {
          mn = mr[qi];
        } else {
          mn = fmaxf(mr[qi], tm);
          float sc = __expf(mr[qi] - mn);
          mr[qi] = mn;
          lr[qi] *= sc;
          float scb[4];
#pragma unroll
          for (int r = 0; r < 4; ++r) scb[r] = __shfl(sc, lk * 4 + r);
#pragma unroll
          for (int dt = 0; dt < 8; ++dt)
#pragma unroll
            for (int r = 0; r < 4; ++r) oa[qi][dt][r] *= scb[r];
        }
        float ts = 0.f;
#pragma unroll
        for (int ktc = 0; ktc < 4; ++ktc)
#pragma unroll
          for (int r = 0; r < 4; ++r) {
            float e = __expf(p[ktc][r] - mn);
            p[ktc][r] = e;
            ts += e;
          }
        ts += __shfl_xor(ts, 16);
        ts += __shfl_xor(ts, 32);
        lr[qi] += ts;
        // packed P write (b64, swizzled, per-wave)
        char* pq = pw + (qi * 16 + la) * 128;
#pragma unroll
        for (int ktc = 0; ktc < 4; ++ktc) {
          uint2 gv;
          gv.x = pack2bf(p[ktc][0], p[ktc][1]);
          gv.y = pack2bf(p[ktc][2], p[ktc][3]);
          *(uint2*)(pq + ((32 * ktc + 8 * lk) ^ ((la & 7) << 4))) = gv;
        }
      }
      asm volatile("s_waitcnt lgkmcnt(0)" ::: "memory");
#pragma unroll
      for (int qi = 0; qi < 2; ++qi)
#pragma unroll
        for (int ks = 0; ks < 2; ++ks)
          pf[qi][ks] = __builtin_bit_cast(
              bf16x8_t, *(const ushort8*)(pw + (qi * 16 + la) * 128 +
                                          ((64 * ks + 16 * lk) ^ ((la & 7) << 4))));
    }

    __syncthreads();  // bar1: all waves done reading Ks; V[kt] staging fully landed (wave-uniform)
    if (kt + 1 < kte) STAGE_K(kt + 1);  // flies under PV[kt]

    if (active) {
      __builtin_amdgcn_s_setprio(1);
#pragma unroll
      for (int dt = 0; dt < 8; ++dt) {
        int d = dt * 16 + la;
#pragma unroll
        for (int ks = 0; ks < 2; ++ks) {
          bf16x8_t vf = __builtin_bit_cast(
              bf16x8_t, *(const ushort8*)(Vsb + d * 128 + ((((ks << 2) + lk) ^ (d & 7)) << 4)));
          oa[0][dt] = __builtin_amdgcn_mfma_f32_16x16x32_bf16(pf[0][ks], vf, oa[0][dt], 0, 0, 0);
          oa[1][dt] = __builtin_amdgcn_mfma_f32_16x16x32_bf16(pf[1][ks], vf, oa[1][dt], 0, 0, 0);
        }
      }
      __builtin_amdgcn_s_setprio(0);
    }

    __syncthreads();  // bar2: drains K[kt+1]; all waves done reading Vs
    if (kt + 1 < kte) STAGE_V(kt + 1);  // flies under QK[kt+1]+softmax
  }

  if (full) {
#pragma unroll
    for (int qi = 0; qi < 2; ++qi) {
      float inv = 1.f / lr[qi];
      float invb[4];
#pragma unroll
      for (int r = 0; r < 4; ++r) invb[r] = __shfl(inv, lk * 4 + r);
#pragma unroll
      for (int dt = 0; dt < 8; ++dt)
#pragma unroll
        for (int r = 0; r < 4; ++r)
          Ob[(size_t)(b * S + qw + qi * 16 + lk * 4 + r) * 2048 + h * 128 + dt * 16 + la] =
              f2bf(oa[qi][dt][r] * invb[r]);
    }
  } else {
    const int slot = (b * 16 + h) * 8 + (qt - 8);
    unsigned short* op = oP + ((size_t)slot * 2 + c) * (128 * 128);
    float* ml = mlP + ((size_t)slot * 2 + c) * 256;
#pragma unroll
    for (int qi = 0; qi < 2; ++qi) {
      if (lk == 0) {
        ml[w * 32 + qi * 16 + la] = mr[qi];
        ml[128 + w * 32 + qi * 16 + la] = lr[qi];
      }
      float inv = 1.f / lr[qi];
      float invb[4];
#pragma unroll
      for (int r = 0; r < 4; ++r) invb[r] = __shfl(inv, lk * 4 + r);
#pragma unroll
      for (int dt = 0; dt < 8; ++dt)
#pragma unroll
        for (int r = 0; r < 4; ++r)
          op[(size_t)(w * 32 + qi * 16 + lk * 4 + r) * 128 + dt * 16 + la] =
              f2bf(oa[qi][dt][r] * invb[r]);
    }
  }
#undef STAGE_K
#undef STAGE_V
}

// ---------- combine partial attention outputs (qt >= 8) ----------
__global__ __launch_bounds__(256) void combine_k(const unsigned short* __restrict__ oP,
                                                 const float* __restrict__ mlP,
                                                 unsigned short* __restrict__ Ob) {
  const int slot = blockIdx.x;  // ((b*16+h)*8 + qt-8)
  const int b = slot >> 7, h = (slot >> 3) & 15, qt = 8 + (slot & 7);
  const int t = threadIdx.x;
  const int r = t >> 1, half = t & 1;
  const float* ml0 = mlP + (size_t)slot * 512;
  const float* ml1 = ml0 + 256;
  float m0 = ml0[r], l0 = ml0[128 + r], m1 = ml1[r], l1 = ml1[128 + r];
  float M = fmaxf(m0, m1);
  float w0 = l0 * __expf(m0 - M), w1 = l1 * __expf(m1 - M);
  float inv = 1.f / (w0 + w1);
  w0 *= inv;
  w1 *= inv;
  const unsigned short* o0 = oP + (size_t)slot * 2 * 16384 + r * 128 + half * 64;
  const unsigned short* o1 = o0 + 16384;
  unsigned short* ob = Ob + (size_t)(b * 2048 + qt * 128 + r) * 2048 + h * 128 + half * 64;
#pragma unroll
  for (int j = 0; j < 64; j += 8) {
    ushort8 a = *(const ushort8*)(o0 + j);
    ushort8 c = *(const ushort8*)(o1 + j);
    ushort8 o;
#pragma unroll
    for (int e = 0; e < 8; ++e) o[e] = f2bf(w0 * b2f(a[e]) + w1 * b2f(c[e]));
    *(ushort8*)(ob + j) = o;
  }
}

extern "C" void kernel_launch(void* const* d_in, const int* in_sizes, int n_in,
                              void* d_out, int out_size, void* d_ws, size_t ws_size,
                              hipStream_t stream) {
  const float* x = (const float*)d_in[0];
  const float* rc = (const float*)d_in[1];
  const float* rs = (const float*)d_in[2];
  const float* Wq = (const float*)d_in[3];
  const float* Wk = (const float*)d_in[4];
  const float* Wv = (const float*)d_in[5];
  const float* Wo = (const float*)d_in[6];
  float* out = (float*)d_out;

  const int B = 2, S = 2048, DM = 2048;
  const int M = B * S;  // 4096

  // workspace (bf16 elems): xb | QKV | WallT (later WoT + Vt) | oP | mlP
  unsigned short* xb = (unsigned short*)d_ws;              // M x 2048      (16 MB)
  unsigned short* QKV = xb + (size_t)M * DM;               // M x 3072      (25.2 MB)
  unsigned short* WallT = QKV + (size_t)M * 3072;          // 3072 x 2048   (12.6 MB)
  unsigned short* WoT = WallT;                             // alias (after QKV proj)
  unsigned short* Vt = WallT + (size_t)2048 * 2048;        // 1024 x 2048 (4 MB, dead Wk/Wv rows)
  unsigned short* Ob = xb;                                 // alias (x dead after proj)
  unsigned short* oP = WallT + (size_t)3072 * 2048;        // 256 slots x 2 x 128 x 128 (16 MB)
  float* mlP = (float*)(oP + (size_t)256 * 2 * 16384);     // 256 x 2 x 256 fp32 (0.5 MB)

  dim3 blk(256);

  // prepass
  cvt_k<<<(M * DM / 8 + 255) / 256, blk, 0, stream>>>(x, xb, M * DM / 8);
  twc_k<<<dim3(64, 64), dim3(32, 8), 0, stream>>>(Wq, WallT, DM, DM);
  twc_k<<<dim3(64, 16), dim3(32, 8), 0, stream>>>(Wk, WallT + (size_t)2048 * DM, DM, 512);
  twc_k<<<dim3(64, 16), dim3(32, 8), 0, stream>>>(Wv, WallT + (size_t)2560 * DM, DM, 512);

  // fused QKV projection + RoPE on cols < 2560 (Q and K regions)
  gemm_tn<true, true><<<dim3(3072 / 128, M / 128), blk, 0, stream>>>(xb, WallT, QKV, M, 3072, DM,
                                                                     rc, rs, 2560);

  // Wo transpose (overwrites WallT rows 0..2047)
  twc_k<<<dim3(64, 64), dim3(32, 8), 0, stream>>>(Wo, WoT, DM, DM);

  transpose_v<<<dim3(S / 32, 4, B * 4), dim3(32, 8), 0, stream>>>(QKV, Vt);

  attn_mfma<<<dim3(24, 16, B), blk, 0, stream>>>(QKV, Vt, Ob, oP, mlP);
  combine_k<<<dim3(256), blk, 0, stream>>>(oP, mlP, Ob);

  gemm_tn<false, false><<<dim3(DM / 128, M / 128), blk, 0, stream>>>(Ob, WoT, out, M, DM, DM,
                                                                     nullptr, nullptr, 0);
}

// Round 18
// 233.024 us; speedup vs baseline: 1.5800x; 1.1215x over previous
//
#include <hip/hip_runtime.h>
#include <hip/hip_bf16.h>
#include <math.h>

typedef __bf16 bf16x8_t __attribute__((ext_vector_type(8)));
typedef float f32x4 __attribute__((ext_vector_type(4)));
typedef unsigned short ushort8 __attribute__((ext_vector_type(8)));

__device__ inline unsigned short f2bf(float f) {
  unsigned int u = __builtin_bit_cast(unsigned int, f);
  u += 0x7fffu + ((u >> 16) & 1u);
  return (unsigned short)(u >> 16);
}
__device__ inline float b2f(unsigned short s) {
  unsigned int u = ((unsigned int)s) << 16;
  return __builtin_bit_cast(float, u);
}
__device__ inline unsigned int pack2bf(float lo, float hi) {
  return (unsigned int)f2bf(lo) | ((unsigned int)f2bf(hi) << 16);
}

__device__ __forceinline__ void gll16(const void* g, void* l) {
  __builtin_amdgcn_global_load_lds((const __attribute__((address_space(1))) void*)g,
                                   (__attribute__((address_space(3))) void*)l, 16, 0, 0);
}

// ---------- prepass: fp32 -> bf16 convert ----------
__global__ void cvt_k(const float* __restrict__ X, unsigned short* __restrict__ Xb, int total8) {
  int i = blockIdx.x * blockDim.x + threadIdx.x;
  if (i >= total8) return;
  const float4* p = (const float4*)X + 2 * (size_t)i;
  float4 a = p[0], b = p[1];
  ushort8 v;
  v[0] = f2bf(a.x); v[1] = f2bf(a.y); v[2] = f2bf(a.z); v[3] = f2bf(a.w);
  v[4] = f2bf(b.x); v[5] = f2bf(b.y); v[6] = f2bf(b.z); v[7] = f2bf(b.w);
  ((ushort8*)Xb)[i] = v;
}

// ---------- prepass: transpose + convert: Wt[n][k] = bf16(W[k][n]) ----------
__global__ void twc_k(const float* __restrict__ W, unsigned short* __restrict__ Wt, int K, int N) {
  __shared__ float tile[32][33];
  int k0 = blockIdx.x * 32, n0 = blockIdx.y * 32;
  int tx = threadIdx.x, ty = threadIdx.y;  // 32 x 8
#pragma unroll
  for (int i = 0; i < 32; i += 8) tile[ty + i][tx] = W[(size_t)(k0 + ty + i) * N + n0 + tx];
  __syncthreads();
#pragma unroll
  for (int i = 0; i < 32; i += 8)
    Wt[(size_t)(n0 + ty + i) * K + k0 + tx] = f2bf(tile[tx][ty + i]);
}

// ---------- 2-phase pipelined GEMM: C[M][N] = A[M][K] @ Bt[N][K]^T, fused RoPE, XCD swizzle ----------
// Double-buffered LDS; one barrier per K-step; next tile's gll16 issued before compute.
// T1: flat block-id remapped so each XCD gets a contiguous tile chunk (nwg % 8 == 0).
template <bool OUT_BF16, bool ROPE>
__global__ __launch_bounds__(256) void gemm_tn(const unsigned short* __restrict__ A,
                                               const unsigned short* __restrict__ Bt,
                                               void* __restrict__ Cv, int M, int N, int K,
                                               const float* __restrict__ cs,
                                               const float* __restrict__ sn, int ropeLim) {
  __shared__ __align__(16) unsigned short As[2][128 * 32];
  __shared__ __align__(16) unsigned short Bs[2][128 * 32];
  const int t = threadIdx.x, w = t >> 6, lane = t & 63;
  const int la = lane & 15, lk = lane >> 4;
  const int wr = w >> 1, wc = w & 1;
  // XCD-aware swizzle (bijective: gridDim.x*gridDim.y divisible by 8)
  const int nwg = gridDim.x * gridDim.y;
  const int flat = blockIdx.y * gridDim.x + blockIdx.x;
  const int swz = (flat & 7) * (nwg >> 3) + (flat >> 3);
  const int bxs = swz % gridDim.x, bys = swz / gridDim.x;
  const int bm = bys * 128, bn = bxs * 128;
  const int lrow = lane >> 2, lcb = (lane & 3) * 8;

  const unsigned short* Ab = A + (size_t)(bm + (w * 2) * 16 + lrow) * K + lcb;
  const unsigned short* Ab1 = A + (size_t)(bm + (w * 2 + 1) * 16 + lrow) * K + lcb;
  const unsigned short* Bb = Bt + (size_t)(bn + (w * 2) * 16 + lrow) * K + lcb;
  const unsigned short* Bb1 = Bt + (size_t)(bn + (w * 2 + 1) * 16 + lrow) * K + lcb;
  const int c0 = w * 2, c1 = w * 2 + 1;

  f32x4 acc[4][4] = {};

  gll16(Ab, (char*)As[0] + c0 * 1024);
  gll16(Ab1, (char*)As[0] + c1 * 1024);
  gll16(Bb, (char*)Bs[0] + c0 * 1024);
  gll16(Bb1, (char*)Bs[0] + c1 * 1024);

  const int nt = K / 32;
  int cur = 0;
  for (int kt = 0; kt < nt; ++kt) {
    __syncthreads();  // drains gll16 (buf[cur] ready); prior reads of buf[cur^1] done
    if (kt + 1 < nt) {
      const int kn = (kt + 1) * 32;
      gll16(Ab + kn, (char*)As[cur ^ 1] + c0 * 1024);
      gll16(Ab1 + kn, (char*)As[cur ^ 1] + c1 * 1024);
      gll16(Bb + kn, (char*)Bs[cur ^ 1] + c0 * 1024);
      gll16(Bb1 + kn, (char*)Bs[cur ^ 1] + c1 * 1024);
    }

    bf16x8_t a[4], b[4];
#pragma unroll
    for (int m = 0; m < 4; ++m)
      a[m] = __builtin_bit_cast(
          bf16x8_t, *(const ushort8*)(As[cur] + (wr * 64 + m * 16 + la) * 32 + lk * 8));
#pragma unroll
    for (int n = 0; n < 4; ++n)
      b[n] = __builtin_bit_cast(
          bf16x8_t, *(const ushort8*)(Bs[cur] + (wc * 64 + n * 16 + la) * 32 + lk * 8));
#pragma unroll
    for (int m = 0; m < 4; ++m)
#pragma unroll
      for (int n = 0; n < 4; ++n)
        acc[m][n] = __builtin_amdgcn_mfma_f32_16x16x32_bf16(a[m], b[n], acc[m][n], 0, 0, 0);
    cur ^= 1;
  }

#pragma unroll
  for (int m = 0; m < 4; ++m) {
#pragma unroll
    for (int n = 0; n < 4; ++n) {
      const int col = bn + wc * 64 + n * 16 + la;
      const bool doRope = ROPE && (col < ropeLim);  // uniform per block (ropeLim % 128 == 0)
#pragma unroll
      for (int r = 0; r < 4; ++r) {
        int row = bm + wr * 64 + m * 16 + lk * 4 + r;
        float val = acc[m][n][r];
        if (ROPE) {
          float pval = __shfl_xor(val, 1);  // partner column (col ^ 1), same row
          if (doRope) {
            int srow = row & 2047;
            int i = (col & 127) >> 1;
            float cc = cs[srow * 64 + i], ss = sn[srow * 64 + i];
            val = (la & 1) ? (pval * ss + val * cc) : (val * cc - pval * ss);
          }
        }
        if (OUT_BF16)
          ((unsigned short*)Cv)[(size_t)row * N + col] = f2bf(val);
        else
          ((float*)Cv)[(size_t)row * N + col] = val;
      }
    }
  }
}

// ---------- V transpose: Vt[(b*4+g)*128 + d][s] = QKV[(b*2048+s)*3072 + 2560 + g*128 + d] ----------
__global__ void transpose_v(const unsigned short* __restrict__ QKV, unsigned short* __restrict__ Vt) {
  __shared__ unsigned short tile[32][33];
  int bg = blockIdx.z;
  int b = bg >> 2, g = bg & 3;
  int s0 = blockIdx.x * 32, d0 = blockIdx.y * 32;
  int tx = threadIdx.x, ty = threadIdx.y;  // 32 x 8
#pragma unroll
  for (int i = 0; i < 32; i += 8)
    tile[ty + i][tx] = QKV[((size_t)(b * 2048 + s0 + ty + i)) * 3072 + 2560 + g * 128 + d0 + tx];
  __syncthreads();
#pragma unroll
  for (int i = 0; i < 32; i += 8)
    Vt[((size_t)(bg * 128 + d0 + ty + i)) * 2048 + s0 + tx] = tile[tx][ty + i];
}

// ---------- MFMA flash attention (R14 structure — measured best, 95 us) ----------
// 4 waves x 32 q-rows (2 subtiles), kv-tile 64, swapped QK^T, packed-P LDS,
// gll16 double-buffer pipeline, heavy+light qt pairing, defer-max.
// grid (S/128, 16 heads, B), block 256.
__global__ __launch_bounds__(256, 2) void attn_mfma(const unsigned short* __restrict__ QKV,
                                                    const unsigned short* __restrict__ Vt,
                                                    unsigned short* __restrict__ Ob) {
  const int S = 2048;
  __shared__ __align__(16) unsigned short Ks[2][64 * 128];   // linear [krow][d], pre-swizzled
  __shared__ __align__(16) unsigned short Vs[2][128 * 64];   // linear [d][kv], pre-swizzled
  __shared__ __align__(16) unsigned short Ps[4 * 32 * 64];   // per-wave packed P

  const int t = threadIdx.x;
  const int w = t >> 6, lane = t & 63;
  const int la = lane & 15, lk = lane >> 4;
  const int b = blockIdx.z, h = blockIdx.y, g = h >> 2;
  // heavy+light pairing: blocks i and i+256 (same CU under round-robin) get qt summing to 15
  const int qt = (b == 0) ? (gridDim.x - 1 - blockIdx.x) : blockIdx.x;
  const int q0 = qt * 128;
  const int qw = q0 + w * 32;
  const float scale = 0.08838834764831845f;  // 1/sqrt(128)

  // staging: wave w stages K groups 4w..4w+3 (4 rows x 16 chunks) and V groups (8 rows x 8 chunks)
  const unsigned short* ksrc[4];
  const unsigned short* vsrc[4];
#pragma unroll
  for (int u = 0; u < 4; ++u) {
    int kr = 16 * w + 4 * u + (lane >> 4);
    int kp = lane & 15;
    ksrc[u] = QKV + (size_t)(b * S + kr) * 3072 + 2048 + g * 128 + (kp ^ (kr & 7)) * 8;
    int vr = 32 * w + 8 * u + (lane >> 3);
    int vp = lane & 7;
    vsrc[u] = Vt + (size_t)((b * 4 + g) * 128 + vr) * 2048 + (vp ^ (vr & 7)) * 8;
  }

  // Q fragments: qf[qi][dt] at q-row = qw + qi*16 + la, d = dt*32 + lk*8 + i
  bf16x8_t qf[2][4];
#pragma unroll
  for (int qi = 0; qi < 2; ++qi)
#pragma unroll
    for (int dt = 0; dt < 4; ++dt)
      qf[qi][dt] = __builtin_bit_cast(
          bf16x8_t, *(const ushort8*)(QKV + (size_t)(b * S + qw + qi * 16 + la) * 3072 + h * 128 +
                                      dt * 32 + lk * 8));

  f32x4 oa[2][8];
#pragma unroll
  for (int qi = 0; qi < 2; ++qi)
#pragma unroll
    for (int dt = 0; dt < 8; ++dt) oa[qi][dt] = (f32x4){0.f, 0.f, 0.f, 0.f};
  float mr[2] = {-1e30f, -1e30f}, lr[2] = {0.f, 0.f};

  const int n_kt = 2 * qt + 2;
  const int kmask0 = qw & ~63;  // the single partially-masked kv tile for this wave
  char* pw = (char*)Ps + w * 4096;

  // prologue: stage tile 0 into buf 0
#pragma unroll
  for (int u = 0; u < 4; ++u) {
    gll16(ksrc[u], (char*)Ks[0] + (4 * w + u) * 1024);
    gll16(vsrc[u], (char*)Vs[0] + (4 * w + u) * 1024);
  }
  __syncthreads();

  int cur = 0;
  for (int kt = 0; kt < n_kt; ++kt) {
    const int k0 = kt * 64;
    // prefetch next tile into the other buffer
    if (kt + 1 < n_kt) {
      const int kn = k0 + 64;
#pragma unroll
      for (int u = 0; u < 4; ++u) {
        gll16(ksrc[u] + (size_t)kn * 3072, (char*)Ks[cur ^ 1] + (4 * w + u) * 1024);
        gll16(vsrc[u] + kn, (char*)Vs[cur ^ 1] + (4 * w + u) * 1024);
      }
    }

    if (k0 <= qw + 31) {  // wave not fully masked
      char* Ksb = (char*)Ks[cur];
      char* Vsb = (char*)Vs[cur];

      // swapped QK^T: sacc[qi][ktc] = S^T tile: row = kv (lk*4+r within ktc), col = q (la)
      f32x4 sacc[2][4];
#pragma unroll
      for (int qi = 0; qi < 2; ++qi)
#pragma unroll
        for (int ktc = 0; ktc < 4; ++ktc) sacc[qi][ktc] = (f32x4){0.f, 0.f, 0.f, 0.f};
      __builtin_amdgcn_s_setprio(1);
#pragma unroll
      for (int ktc = 0; ktc < 4; ++ktc) {
        int row = ktc * 16 + la;
#pragma unroll
        for (int dt = 0; dt < 4; ++dt) {
          bf16x8_t kf = __builtin_bit_cast(
              bf16x8_t, *(const ushort8*)(Ksb + row * 256 + ((((dt << 2) + lk) ^ (row & 7)) << 4)));
          sacc[0][ktc] = __builtin_amdgcn_mfma_f32_16x16x32_bf16(kf, qf[0][dt], sacc[0][ktc], 0, 0, 0);
          sacc[1][ktc] = __builtin_amdgcn_mfma_f32_16x16x32_bf16(kf, qf[1][dt], sacc[1][ktc], 0, 0, 0);
        }
      }
      __builtin_amdgcn_s_setprio(0);

      const bool domask = (k0 == kmask0);
#pragma unroll
      for (int qi = 0; qi < 2; ++qi) {
        const int q = qw + qi * 16 + la;  // this lane's softmax row
        float p[4][4];
        float tm = -1e30f;
#pragma unroll
        for (int ktc = 0; ktc < 4; ++ktc)
#pragma unroll
          for (int r = 0; r < 4; ++r) {
            float sv = sacc[qi][ktc][r] * scale;
            if (domask && (k0 + ktc * 16 + lk * 4 + r > q)) sv = -1e30f;
            p[ktc][r] = sv;
            tm = fmaxf(tm, sv);
          }
        tm = fmaxf(tm, __shfl_xor(tm, 16));
        tm = fmaxf(tm, __shfl_xor(tm, 32));
        // defer-max (T13): skip rescale when tile max growth is small
        float mn;
        if (__all(tm - mr[qi] <= 8.f)) {
          mn = mr[qi];  // keep old max; P bounded by e^8
        } else {
          mn = fmaxf(mr[qi], tm);
          float sc = __expf(mr[qi] - mn);
          mr[qi] = mn;
          lr[qi] *= sc;
          float scb[4];
#pragma unroll
          for (int r = 0; r < 4; ++r) scb[r] = __shfl(sc, lk * 4 + r);
#pragma unroll
          for (int dt = 0; dt < 8; ++dt)
#pragma unroll
            for (int r = 0; r < 4; ++r) oa[qi][dt][r] *= scb[r];
        }
        float ts = 0.f;
#pragma unroll
        for (int ktc = 0; ktc < 4; ++ktc)
#pragma unroll
          for (int r = 0; r < 4; ++r) {
            float e = __expf(p[ktc][r] - mn);
            p[ktc][r] = e;
            ts += e;
          }
        ts += __shfl_xor(ts, 16);
        ts += __shfl_xor(ts, 32);
        lr[qi] += ts;
        // pack P pairs (consecutive kv) and write b64 to swizzled per-wave LDS
        char* pq = pw + (qi * 16 + la) * 128;
#pragma unroll
        for (int ktc = 0; ktc < 4; ++ktc) {
          uint2 gv;
          gv.x = pack2bf(p[ktc][0], p[ktc][1]);
          gv.y = pack2bf(p[ktc][2], p[ktc][3]);
          *(uint2*)(pq + ((32 * ktc + 8 * lk) ^ ((la & 7) << 4))) = gv;
        }
      }
      asm volatile("s_waitcnt lgkmcnt(0)" ::: "memory");

      // P fragments: pf[qi][ks] = P[q = qi*16+la][kv = ks*32 + lk*8 + i]
      bf16x8_t pf[2][2];
#pragma unroll
      for (int qi = 0; qi < 2; ++qi)
#pragma unroll
        for (int ks = 0; ks < 2; ++ks)
          pf[qi][ks] = __builtin_bit_cast(
              bf16x8_t, *(const ushort8*)(pw + (qi * 16 + la) * 128 +
                                          ((64 * ks + 16 * lk) ^ ((la & 7) << 4))));
      __builtin_amdgcn_s_setprio(1);
#pragma unroll
      for (int dt = 0; dt < 8; ++dt) {
        int d = dt * 16 + la;
#pragma unroll
        for (int ks = 0; ks < 2; ++ks) {
          bf16x8_t vf = __builtin_bit_cast(
              bf16x8_t, *(const ushort8*)(Vsb + d * 128 + ((((ks << 2) + lk) ^ (d & 7)) << 4)));
          oa[0][dt] = __builtin_amdgcn_mfma_f32_16x16x32_bf16(pf[0][ks], vf, oa[0][dt], 0, 0, 0);
          oa[1][dt] = __builtin_amdgcn_mfma_f32_16x16x32_bf16(pf[1][ks], vf, oa[1][dt], 0, 0, 0);
        }
      }
      __builtin_amdgcn_s_setprio(0);
    }

    __syncthreads();  // prefetched tile landed; all reads of cur done
    cur ^= 1;
  }

#pragma unroll
  for (int qi = 0; qi < 2; ++qi) {
    float inv = 1.f / lr[qi];
    float invb[4];
#pragma unroll
    for (int r = 0; r < 4; ++r) invb[r] = __shfl(inv, lk * 4 + r);
#pragma unroll
    for (int dt = 0; dt < 8; ++dt)
#pragma unroll
      for (int r = 0; r < 4; ++r)
        Ob[(size_t)(b * S + qw + qi * 16 + lk * 4 + r) * 2048 + h * 128 + dt * 16 + la] =
            f2bf(oa[qi][dt][r] * invb[r]);
  }
}

extern "C" void kernel_launch(void* const* d_in, const int* in_sizes, int n_in,
                              void* d_out, int out_size, void* d_ws, size_t ws_size,
                              hipStream_t stream) {
  const float* x = (const float*)d_in[0];
  const float* rc = (const float*)d_in[1];
  const float* rs = (const float*)d_in[2];
  const float* Wq = (const float*)d_in[3];
  const float* Wk = (const float*)d_in[4];
  const float* Wv = (const float*)d_in[5];
  const float* Wo = (const float*)d_in[6];
  float* out = (float*)d_out;

  const int B = 2, S = 2048, DM = 2048;
  const int M = B * S;  // 4096

  // workspace (bf16 elems): xb | QKV | WallT (later WoT + Vt)
  unsigned short* xb = (unsigned short*)d_ws;              // M x 2048      (16 MB)
  unsigned short* QKV = xb + (size_t)M * DM;               // M x 3072      (25.2 MB)
  unsigned short* WallT = QKV + (size_t)M * 3072;          // 3072 x 2048   (12.6 MB)
  unsigned short* WoT = WallT;                             // alias (after QKV proj)
  unsigned short* Vt = WallT + (size_t)2048 * 2048;        // 1024 x 2048 (4 MB, dead Wk/Wv rows)
  unsigned short* Ob = xb;                                 // alias (x dead after proj)

  dim3 blk(256);

  // prepass
  cvt_k<<<(M * DM / 8 + 255) / 256, blk, 0, stream>>>(x, xb, M * DM / 8);
  twc_k<<<dim3(64, 64), dim3(32, 8), 0, stream>>>(Wq, WallT, DM, DM);
  twc_k<<<dim3(64, 16), dim3(32, 8), 0, stream>>>(Wk, WallT + (size_t)2048 * DM, DM, 512);
  twc_k<<<dim3(64, 16), dim3(32, 8), 0, stream>>>(Wv, WallT + (size_t)2560 * DM, DM, 512);

  // fused QKV projection + RoPE on cols < 2560 (Q and K regions)
  gemm_tn<true, true><<<dim3(3072 / 128, M / 128), blk, 0, stream>>>(xb, WallT, QKV, M, 3072, DM,
                                                                     rc, rs, 2560);

  // Wo transpose (overwrites WallT rows 0..2047)
  twc_k<<<dim3(64, 64), dim3(32, 8), 0, stream>>>(Wo, WoT, DM, DM);

  transpose_v<<<dim3(S / 32, 4, B * 4), dim3(32, 8), 0, stream>>>(QKV, Vt);

  attn_mfma<<<dim3(S / 128, 16, B), dim3(256), 0, stream>>>(QKV, Vt, Ob);

  gemm_tn<false, false><<<dim3(DM / 128, M / 128), blk, 0, stream>>>(Ob, WoT, out, M, DM, DM,
                                                                     nullptr, nullptr, 0);
}

// Round 19
// 228.550 us; speedup vs baseline: 1.6109x; 1.0196x over previous
//
#include <hip/hip_runtime.h>
#include <hip/hip_bf16.h>
#include <math.h>

typedef __bf16 bf16x8_t __attribute__((ext_vector_type(8)));
typedef float f32x4 __attribute__((ext_vector_type(4)));
typedef unsigned short ushort8 __attribute__((ext_vector_type(8)));

__device__ inline unsigned short f2bf(float f) {
  unsigned int u = __builtin_bit_cast(unsigned int, f);
  u += 0x7fffu + ((u >> 16) & 1u);
  return (unsigned short)(u >> 16);
}
__device__ inline float b2f(unsigned short s) {
  unsigned int u = ((unsigned int)s) << 16;
  return __builtin_bit_cast(float, u);
}
__device__ inline unsigned int pack2bf(float lo, float hi) {
  return (unsigned int)f2bf(lo) | ((unsigned int)f2bf(hi) << 16);
}

__device__ __forceinline__ void gll16(const void* g, void* l) {
  __builtin_amdgcn_global_load_lds((const __attribute__((address_space(1))) void*)g,
                                   (__attribute__((address_space(3))) void*)l, 16, 0, 0);
}

// ---------- prepass: fp32 -> bf16 convert ----------
__global__ void cvt_k(const float* __restrict__ X, unsigned short* __restrict__ Xb, int total8) {
  int i = blockIdx.x * blockDim.x + threadIdx.x;
  if (i >= total8) return;
  const float4* p = (const float4*)X + 2 * (size_t)i;
  float4 a = p[0], b = p[1];
  ushort8 v;
  v[0] = f2bf(a.x); v[1] = f2bf(a.y); v[2] = f2bf(a.z); v[3] = f2bf(a.w);
  v[4] = f2bf(b.x); v[5] = f2bf(b.y); v[6] = f2bf(b.z); v[7] = f2bf(b.w);
  ((ushort8*)Xb)[i] = v;
}

// ---------- prepass: ALL weight transposes+converts in one launch ----------
// y in [0,64):   Wq (N=2048) col y*32        -> WallT row y*32
// y in [64,80):  Wk (N=512)  col (y-64)*32   -> WallT row 2048+(y-64)*32
// y in [80,96):  Wv (N=512)  col (y-80)*32   -> WallT row 2560+(y-80)*32
// y in [96,160): Wo (N=2048) col (y-96)*32   -> WoT   row (y-96)*32
__global__ void twc_all(const float* __restrict__ Wq, const float* __restrict__ Wk,
                        const float* __restrict__ Wv, const float* __restrict__ Wo,
                        unsigned short* __restrict__ WallT, unsigned short* __restrict__ WoT) {
  __shared__ float tile[32][33];
  const int K = 2048;
  int y = blockIdx.y;
  const float* W;
  unsigned short* dst;
  int srcN, col0, dstRow0;
  if (y < 64) { W = Wq; srcN = 2048; col0 = y * 32; dst = WallT; dstRow0 = y * 32; }
  else if (y < 80) { W = Wk; srcN = 512; col0 = (y - 64) * 32; dst = WallT; dstRow0 = 2048 + (y - 64) * 32; }
  else if (y < 96) { W = Wv; srcN = 512; col0 = (y - 80) * 32; dst = WallT; dstRow0 = 2560 + (y - 80) * 32; }
  else { W = Wo; srcN = 2048; col0 = (y - 96) * 32; dst = WoT; dstRow0 = (y - 96) * 32; }
  int k0 = blockIdx.x * 32;
  int tx = threadIdx.x, ty = threadIdx.y;  // 32 x 8
#pragma unroll
  for (int i = 0; i < 32; i += 8) tile[ty + i][tx] = W[(size_t)(k0 + ty + i) * srcN + col0 + tx];
  __syncthreads();
#pragma unroll
  for (int i = 0; i < 32; i += 8)
    dst[(size_t)(dstRow0 + ty + i) * K + k0 + tx] = f2bf(tile[tx][ty + i]);
}

// ---------- 2-phase pipelined GEMM: C[M][N] = A[M][K] @ Bt[N][K]^T, fused RoPE, XCD swizzle ----------
template <bool OUT_BF16, bool ROPE>
__global__ __launch_bounds__(256) void gemm_tn(const unsigned short* __restrict__ A,
                                               const unsigned short* __restrict__ Bt,
                                               void* __restrict__ Cv, int M, int N, int K,
                                               const float* __restrict__ cs,
                                               const float* __restrict__ sn, int ropeLim) {
  __shared__ __align__(16) unsigned short As[2][128 * 32];
  __shared__ __align__(16) unsigned short Bs[2][128 * 32];
  const int t = threadIdx.x, w = t >> 6, lane = t & 63;
  const int la = lane & 15, lk = lane >> 4;
  const int wr = w >> 1, wc = w & 1;
  const int nwg = gridDim.x * gridDim.y;
  const int flat = blockIdx.y * gridDim.x + blockIdx.x;
  const int swz = (flat & 7) * (nwg >> 3) + (flat >> 3);
  const int bxs = swz % gridDim.x, bys = swz / gridDim.x;
  const int bm = bys * 128, bn = bxs * 128;
  const int lrow = lane >> 2, lcb = (lane & 3) * 8;

  const unsigned short* Ab = A + (size_t)(bm + (w * 2) * 16 + lrow) * K + lcb;
  const unsigned short* Ab1 = A + (size_t)(bm + (w * 2 + 1) * 16 + lrow) * K + lcb;
  const unsigned short* Bb = Bt + (size_t)(bn + (w * 2) * 16 + lrow) * K + lcb;
  const unsigned short* Bb1 = Bt + (size_t)(bn + (w * 2 + 1) * 16 + lrow) * K + lcb;
  const int c0 = w * 2, c1 = w * 2 + 1;

  f32x4 acc[4][4] = {};

  gll16(Ab, (char*)As[0] + c0 * 1024);
  gll16(Ab1, (char*)As[0] + c1 * 1024);
  gll16(Bb, (char*)Bs[0] + c0 * 1024);
  gll16(Bb1, (char*)Bs[0] + c1 * 1024);

  const int nt = K / 32;
  int cur = 0;
  for (int kt = 0; kt < nt; ++kt) {
    __syncthreads();  // drains gll16 (buf[cur] ready); prior reads of buf[cur^1] done
    if (kt + 1 < nt) {
      const int kn = (kt + 1) * 32;
      gll16(Ab + kn, (char*)As[cur ^ 1] + c0 * 1024);
      gll16(Ab1 + kn, (char*)As[cur ^ 1] + c1 * 1024);
      gll16(Bb + kn, (char*)Bs[cur ^ 1] + c0 * 1024);
      gll16(Bb1 + kn, (char*)Bs[cur ^ 1] + c1 * 1024);
    }

    bf16x8_t a[4], b[4];
#pragma unroll
    for (int m = 0; m < 4; ++m)
      a[m] = __builtin_bit_cast(
          bf16x8_t, *(const ushort8*)(As[cur] + (wr * 64 + m * 16 + la) * 32 + lk * 8));
#pragma unroll
    for (int n = 0; n < 4; ++n)
      b[n] = __builtin_bit_cast(
          bf16x8_t, *(const ushort8*)(Bs[cur] + (wc * 64 + n * 16 + la) * 32 + lk * 8));
#pragma unroll
    for (int m = 0; m < 4; ++m)
#pragma unroll
      for (int n = 0; n < 4; ++n)
        acc[m][n] = __builtin_amdgcn_mfma_f32_16x16x32_bf16(a[m], b[n], acc[m][n], 0, 0, 0);
    cur ^= 1;
  }

#pragma unroll
  for (int m = 0; m < 4; ++m) {
#pragma unroll
    for (int n = 0; n < 4; ++n) {
      const int col = bn + wc * 64 + n * 16 + la;
      const bool doRope = ROPE && (col < ropeLim);  // uniform per block (ropeLim % 128 == 0)
#pragma unroll
      for (int r = 0; r < 4; ++r) {
        int row = bm + wr * 64 + m * 16 + lk * 4 + r;
        float val = acc[m][n][r];
        if (ROPE) {
          float pval = __shfl_xor(val, 1);  // partner column (col ^ 1), same row
          if (doRope) {
            int srow = row & 2047;
            int i = (col & 127) >> 1;
            float cc = cs[srow * 64 + i], ss = sn[srow * 64 + i];
            val = (la & 1) ? (pval * ss + val * cc) : (val * cc - pval * ss);
          }
        }
        if (OUT_BF16)
          ((unsigned short*)Cv)[(size_t)row * N + col] = f2bf(val);
        else
          ((float*)Cv)[(size_t)row * N + col] = val;
      }
    }
  }
}

// ---------- V transpose: Vt[(b*4+g)*128 + d][s] = QKV[(b*2048+s)*3072 + 2560 + g*128 + d] ----------
__global__ void transpose_v(const unsigned short* __restrict__ QKV, unsigned short* __restrict__ Vt) {
  __shared__ unsigned short tile[32][33];
  int bg = blockIdx.z;
  int b = bg >> 2, g = bg & 3;
  int s0 = blockIdx.x * 32, d0 = blockIdx.y * 32;
  int tx = threadIdx.x, ty = threadIdx.y;  // 32 x 8
#pragma unroll
  for (int i = 0; i < 32; i += 8)
    tile[ty + i][tx] = QKV[((size_t)(b * 2048 + s0 + ty + i)) * 3072 + 2560 + g * 128 + d0 + tx];
  __syncthreads();
#pragma unroll
  for (int i = 0; i < 32; i += 8)
    Vt[((size_t)(bg * 128 + d0 + ty + i)) * 2048 + s0 + tx] = tile[tx][ty + i];
}

// ---------- MFMA flash attention (R14 structure — measured best, 95 us) ----------
// 4 waves x 32 q-rows (2 subtiles), kv-tile 64, swapped QK^T, packed-P LDS,
// gll16 double-buffer pipeline, heavy+light qt pairing, defer-max.
// grid (S/128, 16 heads, B), block 256.
__global__ __launch_bounds__(256, 2) void attn_mfma(const unsigned short* __restrict__ QKV,
                                                    const unsigned short* __restrict__ Vt,
                                                    unsigned short* __restrict__ Ob) {
  const int S = 2048;
  __shared__ __align__(16) unsigned short Ks[2][64 * 128];   // linear [krow][d], pre-swizzled
  __shared__ __align__(16) unsigned short Vs[2][128 * 64];   // linear [d][kv], pre-swizzled
  __shared__ __align__(16) unsigned short Ps[4 * 32 * 64];   // per-wave packed P

  const int t = threadIdx.x;
  const int w = t >> 6, lane = t & 63;
  const int la = lane & 15, lk = lane >> 4;
  const int b = blockIdx.z, h = blockIdx.y, g = h >> 2;
  // heavy+light pairing: blocks i and i+256 (same CU under round-robin) get qt summing to 15
  const int qt = (b == 0) ? (gridDim.x - 1 - blockIdx.x) : blockIdx.x;
  const int q0 = qt * 128;
  const int qw = q0 + w * 32;
  const float scale = 0.08838834764831845f;  // 1/sqrt(128)

  // staging: wave w stages K groups 4w..4w+3 (4 rows x 16 chunks) and V groups (8 rows x 8 chunks)
  const unsigned short* ksrc[4];
  const unsigned short* vsrc[4];
#pragma unroll
  for (int u = 0; u < 4; ++u) {
    int kr = 16 * w + 4 * u + (lane >> 4);
    int kp = lane & 15;
    ksrc[u] = QKV + (size_t)(b * S + kr) * 3072 + 2048 + g * 128 + (kp ^ (kr & 7)) * 8;
    int vr = 32 * w + 8 * u + (lane >> 3);
    int vp = lane & 7;
    vsrc[u] = Vt + (size_t)((b * 4 + g) * 128 + vr) * 2048 + (vp ^ (vr & 7)) * 8;
  }

  // Q fragments: qf[qi][dt] at q-row = qw + qi*16 + la, d = dt*32 + lk*8 + i
  bf16x8_t qf[2][4];
#pragma unroll
  for (int qi = 0; qi < 2; ++qi)
#pragma unroll
    for (int dt = 0; dt < 4; ++dt)
      qf[qi][dt] = __builtin_bit_cast(
          bf16x8_t, *(const ushort8*)(QKV + (size_t)(b * S + qw + qi * 16 + la) * 3072 + h * 128 +
                                      dt * 32 + lk * 8));

  f32x4 oa[2][8];
#pragma unroll
  for (int qi = 0; qi < 2; ++qi)
#pragma unroll
    for (int dt = 0; dt < 8; ++dt) oa[qi][dt] = (f32x4){0.f, 0.f, 0.f, 0.f};
  float mr[2] = {-1e30f, -1e30f}, lr[2] = {0.f, 0.f};

  const int n_kt = 2 * qt + 2;
  const int kmask0 = qw & ~63;  // the single partially-masked kv tile for this wave
  char* pw = (char*)Ps + w * 4096;

  // prologue: stage tile 0 into buf 0
#pragma unroll
  for (int u = 0; u < 4; ++u) {
    gll16(ksrc[u], (char*)Ks[0] + (4 * w + u) * 1024);
    gll16(vsrc[u], (char*)Vs[0] + (4 * w + u) * 1024);
  }
  __syncthreads();

  int cur = 0;
  for (int kt = 0; kt < n_kt; ++kt) {
    const int k0 = kt * 64;
    // prefetch next tile into the other buffer
    if (kt + 1 < n_kt) {
      const int kn = k0 + 64;
#pragma unroll
      for (int u = 0; u < 4; ++u) {
        gll16(ksrc[u] + (size_t)kn * 3072, (char*)Ks[cur ^ 1] + (4 * w + u) * 1024);
        gll16(vsrc[u] + kn, (char*)Vs[cur ^ 1] + (4 * w + u) * 1024);
      }
    }

    if (k0 <= qw + 31) {  // wave not fully masked
      char* Ksb = (char*)Ks[cur];
      char* Vsb = (char*)Vs[cur];

      // swapped QK^T: sacc[qi][ktc] = S^T tile: row = kv (lk*4+r within ktc), col = q (la)
      f32x4 sacc[2][4];
#pragma unroll
      for (int qi = 0; qi < 2; ++qi)
#pragma unroll
        for (int ktc = 0; ktc < 4; ++ktc) sacc[qi][ktc] = (f32x4){0.f, 0.f, 0.f, 0.f};
      __builtin_amdgcn_s_setprio(1);
#pragma unroll
      for (int ktc = 0; ktc < 4; ++ktc) {
        int row = ktc * 16 + la;
#pragma unroll
        for (int dt = 0; dt < 4; ++dt) {
          bf16x8_t kf = __builtin_bit_cast(
              bf16x8_t, *(const ushort8*)(Ksb + row * 256 + ((((dt << 2) + lk) ^ (row & 7)) << 4)));
          sacc[0][ktc] = __builtin_amdgcn_mfma_f32_16x16x32_bf16(kf, qf[0][dt], sacc[0][ktc], 0, 0, 0);
          sacc[1][ktc] = __builtin_amdgcn_mfma_f32_16x16x32_bf16(kf, qf[1][dt], sacc[1][ktc], 0, 0, 0);
        }
      }
      __builtin_amdgcn_s_setprio(0);

      const bool domask = (k0 == kmask0);
#pragma unroll
      for (int qi = 0; qi < 2; ++qi) {
        const int q = qw + qi * 16 + la;  // this lane's softmax row
        float p[4][4];
        float tm = -1e30f;
#pragma unroll
        for (int ktc = 0; ktc < 4; ++ktc)
#pragma unroll
          for (int r = 0; r < 4; ++r) {
            float sv = sacc[qi][ktc][r] * scale;
            if (domask && (k0 + ktc * 16 + lk * 4 + r > q)) sv = -1e30f;
            p[ktc][r] = sv;
            tm = fmaxf(tm, sv);
          }
        tm = fmaxf(tm, __shfl_xor(tm, 16));
        tm = fmaxf(tm, __shfl_xor(tm, 32));
        // defer-max (T13): skip rescale when tile max growth is small
        float mn;
        if (__all(tm - mr[qi] <= 8.f)) {
          mn = mr[qi];  // keep old max; P bounded by e^8
        } else {
          mn = fmaxf(mr[qi], tm);
          float sc = __expf(mr[qi] - mn);
          mr[qi] = mn;
          lr[qi] *= sc;
          float scb[4];
#pragma unroll
          for (int r = 0; r < 4; ++r) scb[r] = __shfl(sc, lk * 4 + r);
#pragma unroll
          for (int dt = 0; dt < 8; ++dt)
#pragma unroll
            for (int r = 0; r < 4; ++r) oa[qi][dt][r] *= scb[r];
        }
        float ts = 0.f;
#pragma unroll
        for (int ktc = 0; ktc < 4; ++ktc)
#pragma unroll
          for (int r = 0; r < 4; ++r) {
            float e = __expf(p[ktc][r] - mn);
            p[ktc][r] = e;
            ts += e;
          }
        ts += __shfl_xor(ts, 16);
        ts += __shfl_xor(ts, 32);
        lr[qi] += ts;
        // pack P pairs (consecutive kv) and write b64 to swizzled per-wave LDS
        char* pq = pw + (qi * 16 + la) * 128;
#pragma unroll
        for (int ktc = 0; ktc < 4; ++ktc) {
          uint2 gv;
          gv.x = pack2bf(p[ktc][0], p[ktc][1]);
          gv.y = pack2bf(p[ktc][2], p[ktc][3]);
          *(uint2*)(pq + ((32 * ktc + 8 * lk) ^ ((la & 7) << 4))) = gv;
        }
      }
      asm volatile("s_waitcnt lgkmcnt(0)" ::: "memory");

      // P fragments: pf[qi][ks] = P[q = qi*16+la][kv = ks*32 + lk*8 + i]
      bf16x8_t pf[2][2];
#pragma unroll
      for (int qi = 0; qi < 2; ++qi)
#pragma unroll
        for (int ks = 0; ks < 2; ++ks)
          pf[qi][ks] = __builtin_bit_cast(
              bf16x8_t, *(const ushort8*)(pw + (qi * 16 + la) * 128 +
                                          ((64 * ks + 16 * lk) ^ ((la & 7) << 4))));
      __builtin_amdgcn_s_setprio(1);
#pragma unroll
      for (int dt = 0; dt < 8; ++dt) {
        int d = dt * 16 + la;
#pragma unroll
        for (int ks = 0; ks < 2; ++ks) {
          bf16x8_t vf = __builtin_bit_cast(
              bf16x8_t, *(const ushort8*)(Vsb + d * 128 + ((((ks << 2) + lk) ^ (d & 7)) << 4)));
          oa[0][dt] = __builtin_amdgcn_mfma_f32_16x16x32_bf16(pf[0][ks], vf, oa[0][dt], 0, 0, 0);
          oa[1][dt] = __builtin_amdgcn_mfma_f32_16x16x32_bf16(pf[1][ks], vf, oa[1][dt], 0, 0, 0);
        }
      }
      __builtin_amdgcn_s_setprio(0);
    }

    __syncthreads();  // prefetched tile landed; all reads of cur done
    cur ^= 1;
  }

#pragma unroll
  for (int qi = 0; qi < 2; ++qi) {
    float inv = 1.f / lr[qi];
    float invb[4];
#pragma unroll
    for (int r = 0; r < 4; ++r) invb[r] = __shfl(inv, lk * 4 + r);
#pragma unroll
    for (int dt = 0; dt < 8; ++dt)
#pragma unroll
      for (int r = 0; r < 4; ++r)
        Ob[(size_t)(b * S + qw + qi * 16 + lk * 4 + r) * 2048 + h * 128 + dt * 16 + la] =
            f2bf(oa[qi][dt][r] * invb[r]);
  }
}

extern "C" void kernel_launch(void* const* d_in, const int* in_sizes, int n_in,
                              void* d_out, int out_size, void* d_ws, size_t ws_size,
                              hipStream_t stream) {
  const float* x = (const float*)d_in[0];
  const float* rc = (const float*)d_in[1];
  const float* rs = (const float*)d_in[2];
  const float* Wq = (const float*)d_in[3];
  const float* Wk = (const float*)d_in[4];
  const float* Wv = (const float*)d_in[5];
  const float* Wo = (const float*)d_in[6];
  float* out = (float*)d_out;

  const int B = 2, S = 2048, DM = 2048;
  const int M = B * S;  // 4096

  // workspace (bf16 elems): xb | QKV | WallT | WoT | (Vt in dead WallT rows)
  unsigned short* xb = (unsigned short*)d_ws;              // M x 2048      (16 MB)
  unsigned short* QKV = xb + (size_t)M * DM;               // M x 3072      (25.2 MB)
  unsigned short* WallT = QKV + (size_t)M * 3072;          // 3072 x 2048   (12.6 MB)
  unsigned short* WoT = WallT + (size_t)3072 * DM;         // 2048 x 2048   (8.4 MB)
  unsigned short* Vt = WallT + (size_t)2048 * 2048;        // 1024 x 2048 (4 MB, dead Wk/Wv rows after QKV proj)
  unsigned short* Ob = xb;                                 // alias (x dead after proj)

  dim3 blk(256);

  // prepass: x convert + ALL weight transposes in one launch each
  cvt_k<<<(M * DM / 8 + 255) / 256, blk, 0, stream>>>(x, xb, M * DM / 8);
  twc_all<<<dim3(64, 160), dim3(32, 8), 0, stream>>>(Wq, Wk, Wv, Wo, WallT, WoT);

  // fused QKV projection + RoPE on cols < 2560 (Q and K regions)
  gemm_tn<true, true><<<dim3(3072 / 128, M / 128), blk, 0, stream>>>(xb, WallT, QKV, M, 3072, DM,
                                                                     rc, rs, 2560);

  transpose_v<<<dim3(S / 32, 4, B * 4), dim3(32, 8), 0, stream>>>(QKV, Vt);

  attn_mfma<<<dim3(S / 128, 16, B), dim3(256), 0, stream>>>(QKV, Vt, Ob);

  gemm_tn<false, false><<<dim3(DM / 128, M / 128), blk, 0, stream>>>(Ob, WoT, out, M, DM, DM,
                                                                     nullptr, nullptr, 0);
}

// Round 20
// 225.836 us; speedup vs baseline: 1.6303x; 1.0120x over previous
//
#include <hip/hip_runtime.h>
#include <hip/hip_bf16.h>
#include <math.h>

typedef __bf16 bf16x8_t __attribute__((ext_vector_type(8)));
typedef float f32x4 __attribute__((ext_vector_type(4)));
typedef unsigned short ushort8 __attribute__((ext_vector_type(8)));

__device__ inline unsigned short f2bf(float f) {
  unsigned int u = __builtin_bit_cast(unsigned int, f);
  u += 0x7fffu + ((u >> 16) & 1u);
  return (unsigned short)(u >> 16);
}
__device__ inline float b2f(unsigned short s) {
  unsigned int u = ((unsigned int)s) << 16;
  return __builtin_bit_cast(float, u);
}
__device__ inline unsigned int pack2bf(float lo, float hi) {
  return (unsigned int)f2bf(lo) | ((unsigned int)f2bf(hi) << 16);
}

__device__ __forceinline__ void gll16(const void* g, void* l) {
  __builtin_amdgcn_global_load_lds((const __attribute__((address_space(1))) void*)g,
                                   (__attribute__((address_space(3))) void*)l, 16, 0, 0);
}

// ---------- unified prepass: all weight transposes+converts AND x fp32->bf16 convert ----------
// blocks [0, 10240): weight transpose tiles; flat = bid; ywork = flat/64 in [0,160), k-block = flat%64
//   ywork in [0,64):   Wq col y*32      -> WallT row y*32
//   ywork in [64,80):  Wk col (y-64)*32 -> WallT row 2048+(y-64)*32
//   ywork in [80,96):  Wv col (y-80)*32 -> WallT row 2560+(y-80)*32
//   ywork in [96,160): Wo col (y-96)*32 -> WoT   row (y-96)*32
// blocks [10240, 14336): x convert, i = (bid-10240)*256 + tid over M*DM/8 ushort8 elements
__global__ __launch_bounds__(256) void prep_k(const float* __restrict__ x,
                                              const float* __restrict__ Wq,
                                              const float* __restrict__ Wk,
                                              const float* __restrict__ Wv,
                                              const float* __restrict__ Wo,
                                              unsigned short* __restrict__ xb,
                                              unsigned short* __restrict__ WallT,
                                              unsigned short* __restrict__ WoT) {
  const int bid = blockIdx.x;
  const int tid = threadIdx.x;
  if (bid < 10240) {
    __shared__ float tile[32][33];
    const int K = 2048;
    int y = bid / 64;
    int k0 = (bid % 64) * 32;
    const float* W;
    unsigned short* dst;
    int srcN, col0, dstRow0;
    if (y < 64) { W = Wq; srcN = 2048; col0 = y * 32; dst = WallT; dstRow0 = y * 32; }
    else if (y < 80) { W = Wk; srcN = 512; col0 = (y - 64) * 32; dst = WallT; dstRow0 = 2048 + (y - 64) * 32; }
    else if (y < 96) { W = Wv; srcN = 512; col0 = (y - 80) * 32; dst = WallT; dstRow0 = 2560 + (y - 80) * 32; }
    else { W = Wo; srcN = 2048; col0 = (y - 96) * 32; dst = WoT; dstRow0 = (y - 96) * 32; }
    int tx = tid & 31, ty = tid >> 5;  // 32 x 8
#pragma unroll
    for (int i = 0; i < 32; i += 8) tile[ty + i][tx] = W[(size_t)(k0 + ty + i) * srcN + col0 + tx];
    __syncthreads();
#pragma unroll
    for (int i = 0; i < 32; i += 8)
      dst[(size_t)(dstRow0 + ty + i) * K + k0 + tx] = f2bf(tile[tx][ty + i]);
  } else {
    int i = (bid - 10240) * 256 + tid;  // < 4096*256 = M*DM/8 exactly
    const float4* p = (const float4*)x + 2 * (size_t)i;
    float4 a = p[0], b = p[1];
    ushort8 v;
    v[0] = f2bf(a.x); v[1] = f2bf(a.y); v[2] = f2bf(a.z); v[3] = f2bf(a.w);
    v[4] = f2bf(b.x); v[5] = f2bf(b.y); v[6] = f2bf(b.z); v[7] = f2bf(b.w);
    ((ushort8*)xb)[i] = v;
  }
}

// ---------- 2-phase pipelined GEMM: C[M][N] = A[M][K] @ Bt[N][K]^T, fused RoPE, XCD swizzle ----------
template <bool OUT_BF16, bool ROPE>
__global__ __launch_bounds__(256) void gemm_tn(const unsigned short* __restrict__ A,
                                               const unsigned short* __restrict__ Bt,
                                               void* __restrict__ Cv, int M, int N, int K,
                                               const float* __restrict__ cs,
                                               const float* __restrict__ sn, int ropeLim) {
  __shared__ __align__(16) unsigned short As[2][128 * 32];
  __shared__ __align__(16) unsigned short Bs[2][128 * 32];
  const int t = threadIdx.x, w = t >> 6, lane = t & 63;
  const int la = lane & 15, lk = lane >> 4;
  const int wr = w >> 1, wc = w & 1;
  const int nwg = gridDim.x * gridDim.y;
  const int flat = blockIdx.y * gridDim.x + blockIdx.x;
  const int swz = (flat & 7) * (nwg >> 3) + (flat >> 3);
  const int bxs = swz % gridDim.x, bys = swz / gridDim.x;
  const int bm = bys * 128, bn = bxs * 128;
  const int lrow = lane >> 2, lcb = (lane & 3) * 8;

  const unsigned short* Ab = A + (size_t)(bm + (w * 2) * 16 + lrow) * K + lcb;
  const unsigned short* Ab1 = A + (size_t)(bm + (w * 2 + 1) * 16 + lrow) * K + lcb;
  const unsigned short* Bb = Bt + (size_t)(bn + (w * 2) * 16 + lrow) * K + lcb;
  const unsigned short* Bb1 = Bt + (size_t)(bn + (w * 2 + 1) * 16 + lrow) * K + lcb;
  const int c0 = w * 2, c1 = w * 2 + 1;

  f32x4 acc[4][4] = {};

  gll16(Ab, (char*)As[0] + c0 * 1024);
  gll16(Ab1, (char*)As[0] + c1 * 1024);
  gll16(Bb, (char*)Bs[0] + c0 * 1024);
  gll16(Bb1, (char*)Bs[0] + c1 * 1024);

  const int nt = K / 32;
  int cur = 0;
  for (int kt = 0; kt < nt; ++kt) {
    __syncthreads();  // drains gll16 (buf[cur] ready); prior reads of buf[cur^1] done
    if (kt + 1 < nt) {
      const int kn = (kt + 1) * 32;
      gll16(Ab + kn, (char*)As[cur ^ 1] + c0 * 1024);
      gll16(Ab1 + kn, (char*)As[cur ^ 1] + c1 * 1024);
      gll16(Bb + kn, (char*)Bs[cur ^ 1] + c0 * 1024);
      gll16(Bb1 + kn, (char*)Bs[cur ^ 1] + c1 * 1024);
    }

    bf16x8_t a[4], b[4];
#pragma unroll
    for (int m = 0; m < 4; ++m)
      a[m] = __builtin_bit_cast(
          bf16x8_t, *(const ushort8*)(As[cur] + (wr * 64 + m * 16 + la) * 32 + lk * 8));
#pragma unroll
    for (int n = 0; n < 4; ++n)
      b[n] = __builtin_bit_cast(
          bf16x8_t, *(const ushort8*)(Bs[cur] + (wc * 64 + n * 16 + la) * 32 + lk * 8));
#pragma unroll
    for (int m = 0; m < 4; ++m)
#pragma unroll
      for (int n = 0; n < 4; ++n)
        acc[m][n] = __builtin_amdgcn_mfma_f32_16x16x32_bf16(a[m], b[n], acc[m][n], 0, 0, 0);
    cur ^= 1;
  }

#pragma unroll
  for (int m = 0; m < 4; ++m) {
#pragma unroll
    for (int n = 0; n < 4; ++n) {
      const int col = bn + wc * 64 + n * 16 + la;
      const bool doRope = ROPE && (col < ropeLim);  // uniform per block (ropeLim % 128 == 0)
#pragma unroll
      for (int r = 0; r < 4; ++r) {
        int row = bm + wr * 64 + m * 16 + lk * 4 + r;
        float val = acc[m][n][r];
        if (ROPE) {
          float pval = __shfl_xor(val, 1);  // partner column (col ^ 1), same row
          if (doRope) {
            int srow = row & 2047;
            int i = (col & 127) >> 1;
            float cc = cs[srow * 64 + i], ss = sn[srow * 64 + i];
            val = (la & 1) ? (pval * ss + val * cc) : (val * cc - pval * ss);
          }
        }
        if (OUT_BF16)
          ((unsigned short*)Cv)[(size_t)row * N + col] = f2bf(val);
        else
          ((float*)Cv)[(size_t)row * N + col] = val;
      }
    }
  }
}

// ---------- V transpose: Vt[(b*4+g)*128 + d][s] = QKV[(b*2048+s)*3072 + 2560 + g*128 + d] ----------
__global__ void transpose_v(const unsigned short* __restrict__ QKV, unsigned short* __restrict__ Vt) {
  __shared__ unsigned short tile[32][33];
  int bg = blockIdx.z;
  int b = bg >> 2, g = bg & 3;
  int s0 = blockIdx.x * 32, d0 = blockIdx.y * 32;
  int tx = threadIdx.x, ty = threadIdx.y;  // 32 x 8
#pragma unroll
  for (int i = 0; i < 32; i += 8)
    tile[ty + i][tx] = QKV[((size_t)(b * 2048 + s0 + ty + i)) * 3072 + 2560 + g * 128 + d0 + tx];
  __syncthreads();
#pragma unroll
  for (int i = 0; i < 32; i += 8)
    Vt[((size_t)(bg * 128 + d0 + ty + i)) * 2048 + s0 + tx] = tile[tx][ty + i];
}

// ---------- MFMA flash attention (R14 structure — measured best, 95 us) ----------
// 4 waves x 32 q-rows (2 subtiles), kv-tile 64, swapped QK^T, packed-P LDS,
// gll16 double-buffer pipeline, heavy+light qt pairing, defer-max.
// grid (S/128, 16 heads, B), block 256.
__global__ __launch_bounds__(256, 2) void attn_mfma(const unsigned short* __restrict__ QKV,
                                                    const unsigned short* __restrict__ Vt,
                                                    unsigned short* __restrict__ Ob) {
  const int S = 2048;
  __shared__ __align__(16) unsigned short Ks[2][64 * 128];   // linear [krow][d], pre-swizzled
  __shared__ __align__(16) unsigned short Vs[2][128 * 64];   // linear [d][kv], pre-swizzled
  __shared__ __align__(16) unsigned short Ps[4 * 32 * 64];   // per-wave packed P

  const int t = threadIdx.x;
  const int w = t >> 6, lane = t & 63;
  const int la = lane & 15, lk = lane >> 4;
  const int b = blockIdx.z, h = blockIdx.y, g = h >> 2;
  // heavy+light pairing: blocks i and i+256 (same CU under round-robin) get qt summing to 15
  const int qt = (b == 0) ? (gridDim.x - 1 - blockIdx.x) : blockIdx.x;
  const int q0 = qt * 128;
  const int qw = q0 + w * 32;
  const float scale = 0.08838834764831845f;  // 1/sqrt(128)

  // staging: wave w stages K groups 4w..4w+3 (4 rows x 16 chunks) and V groups (8 rows x 8 chunks)
  const unsigned short* ksrc[4];
  const unsigned short* vsrc[4];
#pragma unroll
  for (int u = 0; u < 4; ++u) {
    int kr = 16 * w + 4 * u + (lane >> 4);
    int kp = lane & 15;
    ksrc[u] = QKV + (size_t)(b * S + kr) * 3072 + 2048 + g * 128 + (kp ^ (kr & 7)) * 8;
    int vr = 32 * w + 8 * u + (lane >> 3);
    int vp = lane & 7;
    vsrc[u] = Vt + (size_t)((b * 4 + g) * 128 + vr) * 2048 + (vp ^ (vr & 7)) * 8;
  }

  // Q fragments: qf[qi][dt] at q-row = qw + qi*16 + la, d = dt*32 + lk*8 + i
  bf16x8_t qf[2][4];
#pragma unroll
  for (int qi = 0; qi < 2; ++qi)
#pragma unroll
    for (int dt = 0; dt < 4; ++dt)
      qf[qi][dt] = __builtin_bit_cast(
          bf16x8_t, *(const ushort8*)(QKV + (size_t)(b * S + qw + qi * 16 + la) * 3072 + h * 128 +
                                      dt * 32 + lk * 8));

  f32x4 oa[2][8];
#pragma unroll
  for (int qi = 0; qi < 2; ++qi)
#pragma unroll
    for (int dt = 0; dt < 8; ++dt) oa[qi][dt] = (f32x4){0.f, 0.f, 0.f, 0.f};
  float mr[2] = {-1e30f, -1e30f}, lr[2] = {0.f, 0.f};

  const int n_kt = 2 * qt + 2;
  const int kmask0 = qw & ~63;  // the single partially-masked kv tile for this wave
  char* pw = (char*)Ps + w * 4096;

  // prologue: stage tile 0 into buf 0
#pragma unroll
  for (int u = 0; u < 4; ++u) {
    gll16(ksrc[u], (char*)Ks[0] + (4 * w + u) * 1024);
    gll16(vsrc[u], (char*)Vs[0] + (4 * w + u) * 1024);
  }
  __syncthreads();

  int cur = 0;
  for (int kt = 0; kt < n_kt; ++kt) {
    const int k0 = kt * 64;
    // prefetch next tile into the other buffer
    if (kt + 1 < n_kt) {
      const int kn = k0 + 64;
#pragma unroll
      for (int u = 0; u < 4; ++u) {
        gll16(ksrc[u] + (size_t)kn * 3072, (char*)Ks[cur ^ 1] + (4 * w + u) * 1024);
        gll16(vsrc[u] + kn, (char*)Vs[cur ^ 1] + (4 * w + u) * 1024);
      }
    }

    if (k0 <= qw + 31) {  // wave not fully masked
      char* Ksb = (char*)Ks[cur];
      char* Vsb = (char*)Vs[cur];

      // swapped QK^T: sacc[qi][ktc] = S^T tile: row = kv (lk*4+r within ktc), col = q (la)
      f32x4 sacc[2][4];
#pragma unroll
      for (int qi = 0; qi < 2; ++qi)
#pragma unroll
        for (int ktc = 0; ktc < 4; ++ktc) sacc[qi][ktc] = (f32x4){0.f, 0.f, 0.f, 0.f};
      __builtin_amdgcn_s_setprio(1);
#pragma unroll
      for (int ktc = 0; ktc < 4; ++ktc) {
        int row = ktc * 16 + la;
#pragma unroll
        for (int dt = 0; dt < 4; ++dt) {
          bf16x8_t kf = __builtin_bit_cast(
              bf16x8_t, *(const ushort8*)(Ksb + row * 256 + ((((dt << 2) + lk) ^ (row & 7)) << 4)));
          sacc[0][ktc] = __builtin_amdgcn_mfma_f32_16x16x32_bf16(kf, qf[0][dt], sacc[0][ktc], 0, 0, 0);
          sacc[1][ktc] = __builtin_amdgcn_mfma_f32_16x16x32_bf16(kf, qf[1][dt], sacc[1][ktc], 0, 0, 0);
        }
      }
      __builtin_amdgcn_s_setprio(0);

      const bool domask = (k0 == kmask0);
#pragma unroll
      for (int qi = 0; qi < 2; ++qi) {
        const int q = qw + qi * 16 + la;  // this lane's softmax row
        float p[4][4];
        float tm = -1e30f;
#pragma unroll
        for (int ktc = 0; ktc < 4; ++ktc)
#pragma unroll
          for (int r = 0; r < 4; ++r) {
            float sv = sacc[qi][ktc][r] * scale;
            if (domask && (k0 + ktc * 16 + lk * 4 + r > q)) sv = -1e30f;
            p[ktc][r] = sv;
            tm = fmaxf(tm, sv);
          }
        tm = fmaxf(tm, __shfl_xor(tm, 16));
        tm = fmaxf(tm, __shfl_xor(tm, 32));
        // defer-max (T13): skip rescale when tile max growth is small
        float mn;
        if (__all(tm - mr[qi] <= 8.f)) {
          mn = mr[qi];  // keep old max; P bounded by e^8
        } else {
          mn = fmaxf(mr[qi], tm);
          float sc = __expf(mr[qi] - mn);
          mr[qi] = mn;
          lr[qi] *= sc;
          float scb[4];
#pragma unroll
          for (int r = 0; r < 4; ++r) scb[r] = __shfl(sc, lk * 4 + r);
#pragma unroll
          for (int dt = 0; dt < 8; ++dt)
#pragma unroll
            for (int r = 0; r < 4; ++r) oa[qi][dt][r] *= scb[r];
        }
        float ts = 0.f;
#pragma unroll
        for (int ktc = 0; ktc < 4; ++ktc)
#pragma unroll
          for (int r = 0; r < 4; ++r) {
            float e = __expf(p[ktc][r] - mn);
            p[ktc][r] = e;
            ts += e;
          }
        ts += __shfl_xor(ts, 16);
        ts += __shfl_xor(ts, 32);
        lr[qi] += ts;
        // pack P pairs (consecutive kv) and write b64 to swizzled per-wave LDS
        char* pq = pw + (qi * 16 + la) * 128;
#pragma unroll
        for (int ktc = 0; ktc < 4; ++ktc) {
          uint2 gv;
          gv.x = pack2bf(p[ktc][0], p[ktc][1]);
          gv.y = pack2bf(p[ktc][2], p[ktc][3]);
          *(uint2*)(pq + ((32 * ktc + 8 * lk) ^ ((la & 7) << 4))) = gv;
        }
      }
      asm volatile("s_waitcnt lgkmcnt(0)" ::: "memory");

      // P fragments: pf[qi][ks] = P[q = qi*16+la][kv = ks*32 + lk*8 + i]
      bf16x8_t pf[2][2];
#pragma unroll
      for (int qi = 0; qi < 2; ++qi)
#pragma unroll
        for (int ks = 0; ks < 2; ++ks)
          pf[qi][ks] = __builtin_bit_cast(
              bf16x8_t, *(const ushort8*)(pw + (qi * 16 + la) * 128 +
                                          ((64 * ks + 16 * lk) ^ ((la & 7) << 4))));
      __builtin_amdgcn_s_setprio(1);
#pragma unroll
      for (int dt = 0; dt < 8; ++dt) {
        int d = dt * 16 + la;
#pragma unroll
        for (int ks = 0; ks < 2; ++ks) {
          bf16x8_t vf = __builtin_bit_cast(
              bf16x8_t, *(const ushort8*)(Vsb + d * 128 + ((((ks << 2) + lk) ^ (d & 7)) << 4)));
          oa[0][dt] = __builtin_amdgcn_mfma_f32_16x16x32_bf16(pf[0][ks], vf, oa[0][dt], 0, 0, 0);
          oa[1][dt] = __builtin_amdgcn_mfma_f32_16x16x32_bf16(pf[1][ks], vf, oa[1][dt], 0, 0, 0);
        }
      }
      __builtin_amdgcn_s_setprio(0);
    }

    __syncthreads();  // prefetched tile landed; all reads of cur done
    cur ^= 1;
  }

#pragma unroll
  for (int qi = 0; qi < 2; ++qi) {
    float inv = 1.f / lr[qi];
    float invb[4];
#pragma unroll
    for (int r = 0; r < 4; ++r) invb[r] = __shfl(inv, lk * 4 + r);
#pragma unroll
    for (int dt = 0; dt < 8; ++dt)
#pragma unroll
      for (int r = 0; r < 4; ++r)
        Ob[(size_t)(b * S + qw + qi * 16 + lk * 4 + r) * 2048 + h * 128 + dt * 16 + la] =
            f2bf(oa[qi][dt][r] * invb[r]);
  }
}

extern "C" void kernel_launch(void* const* d_in, const int* in_sizes, int n_in,
                              void* d_out, int out_size, void* d_ws, size_t ws_size,
                              hipStream_t stream) {
  const float* x = (const float*)d_in[0];
  const float* rc = (const float*)d_in[1];
  const float* rs = (const float*)d_in[2];
  const float* Wq = (const float*)d_in[3];
  const float* Wk = (const float*)d_in[4];
  const float* Wv = (const float*)d_in[5];
  const float* Wo = (const float*)d_in[6];
  float* out = (float*)d_out;

  const int B = 2, S = 2048, DM = 2048;
  const int M = B * S;  // 4096

  // workspace (bf16 elems): xb | QKV | WallT | WoT | (Vt in dead WallT rows)
  unsigned short* xb = (unsigned short*)d_ws;              // M x 2048      (16 MB)
  unsigned short* QKV = xb + (size_t)M * DM;               // M x 3072      (25.2 MB)
  unsigned short* WallT = QKV + (size_t)M * 3072;          // 3072 x 2048   (12.6 MB)
  unsigned short* WoT = WallT + (size_t)3072 * DM;         // 2048 x 2048   (8.4 MB)
  unsigned short* Vt = WallT + (size_t)2048 * 2048;        // 1024 x 2048 (4 MB, dead Wk/Wv rows after QKV proj)
  unsigned short* Ob = xb;                                 // alias (x dead after proj)

  dim3 blk(256);

  // unified prepass: weight transposes + x convert in one launch
  prep_k<<<dim3(14336), blk, 0, stream>>>(x, Wq, Wk, Wv, Wo, xb, WallT, WoT);

  // fused QKV projection + RoPE on cols < 2560 (Q and K regions)
  gemm_tn<true, true><<<dim3(3072 / 128, M / 128), blk, 0, stream>>>(xb, WallT, QKV, M, 3072, DM,
                                                                     rc, rs, 2560);

  transpose_v<<<dim3(S / 32, 4, B * 4), dim3(32, 8), 0, stream>>>(QKV, Vt);

  attn_mfma<<<dim3(S / 128, 16, B), dim3(256), 0, stream>>>(QKV, Vt, Ob);

  gemm_tn<false, false><<<dim3(DM / 128, M / 128), blk, 0, stream>>>(Ob, WoT, out, M, DM, DM,
                                                                     nullptr, nullptr, 0);
}